// Round 3
// baseline (6229.906 us; speedup 1.0000x reference)
//
#include <hip/hip_runtime.h>
#include <hip/hip_bf16.h>
#include <hip/hip_cooperative_groups.h>

namespace cg = cooperative_groups;

// ---------------- workspace layout (float-element offsets) ----------------
#define S_MAX 32
#define VST   2052                    // per-s vector stride (covers nt+1 <= 2048)
#define KSLOT 1057824                 // bf16 elems per s slot >= max (nt+1)*ldp

#define OFF_MAX  64                   // 32 uints (float bits, atomicMax of M)
#define OFF_SUM  96                   // 32 floats (atomicAdd of sum M)
#define OFF_IT   128                  // int[2048] treated indices
#define OFF_IC   2176                 // int[2048] control indices
#define OFF_NORM 4352                 // float[32][2048] row sq-norms -> ends 69888
#define OFF_U    69888                // float[32][VST] current u -> ends 135552
#define OFF_Y    135552               // 2 x 32 x VST y double-buffer -> ends 266880
#define OFF_KF   266880               // bf16 K region; 32*KSLOT ushorts (~64.6 MB)
// total ws usage: 266880*4 + 32*KSLOT*2 = 68,768,256 bytes (~65.6 MiB)

typedef __attribute__((ext_vector_type(8))) short bf16x8;
typedef __attribute__((ext_vector_type(4))) float f32x4;

__device__ __forceinline__ float bf2f(unsigned short u) {
    return __uint_as_float(((unsigned)u) << 16);
}
__device__ __forceinline__ unsigned short f2bf(float f) {
    __hip_bfloat16 h = __float2bfloat16(f);
    return *reinterpret_cast<unsigned short*>(&h);
}
__device__ __forceinline__ bf16x8 cvt8(const float* __restrict__ p) {
    const float4 lo = *(const float4*)p;
    const float4 hi = *(const float4*)(p + 4);
    bf16x8 r;
    r[0] = (short)f2bf(lo.x); r[1] = (short)f2bf(lo.y);
    r[2] = (short)f2bf(lo.z); r[3] = (short)f2bf(lo.w);
    r[4] = (short)f2bf(hi.x); r[5] = (short)f2bf(hi.y);
    r[6] = (short)f2bf(hi.z); r[7] = (short)f2bf(hi.w);
    return r;
}

// ---------------------------------------------------------------------------
// 1) index compaction + meta + u0 = a  (one block)
__global__ __launch_bounds__(1024) void idx_kernel(const int* __restrict__ t, float* __restrict__ ws) {
    __shared__ int sc[2048];
    const int tid = threadIdx.x;
    int p0 = (t[tid] > 0) ? 1 : 0;
    int p1 = (t[tid + 1024] > 0) ? 1 : 0;
    sc[tid] = p0; sc[tid + 1024] = p1;
    __syncthreads();
    for (int off = 1; off < 2048; off <<= 1) {
        int v0 = 0, v1 = 0;
        if (tid >= off)        v0 = sc[tid - off];
        if (tid + 1024 >= off) v1 = sc[tid + 1024 - off];
        __syncthreads();
        sc[tid] += v0; sc[tid + 1024] += v1;
        __syncthreads();
    }
    const int incl0 = sc[tid], incl1 = sc[tid + 1024];
    const int nt = sc[2047];
    const int nc = 2048 - nt;
    int* itl = (int*)(ws + OFF_IT);
    int* icl = (int*)(ws + OFF_IC);
    if (p0) itl[incl0 - 1] = tid;        else icl[tid - incl0] = tid;
    if (p1) itl[incl1 - 1] = tid + 1024; else icl[tid + 1024 - incl1] = tid + 1024;

    const float p = (float)nt / 2048.0f;
    const float a_main = p / (float)nt;
    const float a_last = 1.0f - p;
    if (tid == 0) {
        ((int*)ws)[0] = nt;
        ((int*)ws)[1] = nc;
        ws[2] = p;
        ws[3] = a_main;
        ws[4] = a_last;
        ws[5] = (1.0f - p) / (float)nc;   // b_main
        ws[6] = p;                        // b_last
    }
    for (int s = 0; s < S_MAX; s++) {
        float* u = ws + OFF_U + s * VST;
        for (int i = tid; i < VST; i += 1024)
            u[i] = (i < nt) ? a_main : ((i == nt) ? a_last : 0.0f);
    }
}

// ---------------------------------------------------------------------------
// 2) row squared norms: one wave per (n,s) row of 256 floats
__global__ __launch_bounds__(256) void norm_kernel(const float* __restrict__ enc, float* __restrict__ ws) {
    const int gw = blockIdx.x * 4 + (threadIdx.x >> 6);
    const int lane = threadIdx.x & 63;
    const int n = gw >> 5, s = gw & 31;
    const float4* row = (const float4*)(enc + ((size_t)n * 32 + s) * 256);
    float4 v = row[lane];
    float ss = v.x * v.x + v.y * v.y + v.z * v.z + v.w * v.w;
    for (int off = 32; off; off >>= 1) ss += __shfl_xor(ss, off);
    if (lane == 0) ws[OFF_NORM + s * 2048 + n] = ss;
}

// ---------------------------------------------------------------------------
// 3) M tiles via MFMA bf16: 64x64/block, 4 waves each computing a 32x32 quadrant
//    as 2x2 frags of mfma_f32_16x16x32_bf16. A and B are both row-major [row][k],
//    so both frags load 8 consecutive k at row (lane&15), k-offset (lane>>4)*8.
__global__ __launch_bounds__(256) void m_kernel(const float* __restrict__ enc, float* __restrict__ ws) {
    const int s = blockIdx.z;
    const int nt = ((const int*)ws)[0], nc = ((const int*)ws)[1];
    const int ibase = blockIdx.y * 64, jbase = blockIdx.x * 64;
    if (ibase >= nt || jbase >= nc) return;
    const int ldp = ((nc + 1) + 7) & ~7;

    __shared__ int ridx[64], cidx[64];
    __shared__ float nrmA[64], nrmB[64];
    __shared__ float rmax[4], rsum[4];

    const int tid = threadIdx.x;
    const int* itl = (const int*)(ws + OFF_IT);
    const int* icl = (const int*)(ws + OFF_IC);
    if (tid < 64) {
        int i = ibase + tid;
        int g = itl[(i < nt) ? i : (nt - 1)];
        ridx[tid] = g;
        nrmA[tid] = ws[OFF_NORM + s * 2048 + g];
    } else if (tid < 128) {
        int j = jbase + (tid - 64);
        int g = icl[(j < nc) ? j : (nc - 1)];
        cidx[tid - 64] = g;
        nrmB[tid - 64] = ws[OFF_NORM + s * 2048 + g];
    }
    __syncthreads();

    const int lane = tid & 63, wave = tid >> 6;
    const int wr = wave >> 1, wc = wave & 1;
    const int row16 = lane & 15, koff = (lane >> 4) * 8;
    const int ar0 = wr * 32 + row16;
    const int bc0 = wc * 32 + row16;

    const float* pa0 = enc + ((size_t)ridx[ar0]      * 32 + s) * 256 + koff;
    const float* pa1 = enc + ((size_t)ridx[ar0 + 16] * 32 + s) * 256 + koff;
    const float* pb0 = enc + ((size_t)cidx[bc0]      * 32 + s) * 256 + koff;
    const float* pb1 = enc + ((size_t)cidx[bc0 + 16] * 32 + s) * 256 + koff;

    f32x4 acc00 = {0.f,0.f,0.f,0.f}, acc01 = {0.f,0.f,0.f,0.f};
    f32x4 acc10 = {0.f,0.f,0.f,0.f}, acc11 = {0.f,0.f,0.f,0.f};
    #pragma unroll
    for (int d0 = 0; d0 < 256; d0 += 32) {
        bf16x8 a0 = cvt8(pa0 + d0), a1 = cvt8(pa1 + d0);
        bf16x8 b0 = cvt8(pb0 + d0), b1 = cvt8(pb1 + d0);
        acc00 = __builtin_amdgcn_mfma_f32_16x16x32_bf16(a0, b0, acc00, 0, 0, 0);
        acc01 = __builtin_amdgcn_mfma_f32_16x16x32_bf16(a0, b1, acc01, 0, 0, 0);
        acc10 = __builtin_amdgcn_mfma_f32_16x16x32_bf16(a1, b0, acc10, 0, 0, 0);
        acc11 = __builtin_amdgcn_mfma_f32_16x16x32_bf16(a1, b1, acc11, 0, 0, 0);
    }

    // C/D layout: col = lane&15, row = (lane>>4)*4 + e   [m89]
    unsigned short* Ks = reinterpret_cast<unsigned short*>(ws + OFF_KF) + (size_t)s * KSLOT;
    const int crow = (lane >> 4) * 4;
    const int ccol = lane & 15;
    float lmax = 0.0f, lsum = 0.0f;
    #pragma unroll
    for (int fi = 0; fi < 2; fi++) {
        #pragma unroll
        for (int fj = 0; fj < 2; fj++) {
            f32x4 a = (fi == 0) ? ((fj == 0) ? acc00 : acc01)
                                : ((fj == 0) ? acc10 : acc11);
            #pragma unroll
            for (int e = 0; e < 4; e++) {
                const int ti = wr * 32 + fi * 16 + crow + e;
                const int tj = wc * 32 + fj * 16 + ccol;
                const int i = ibase + ti, j = jbase + tj;
                if (i < nt && j < nc) {
                    float m = nrmA[ti] + nrmB[tj] - 2.0f * a[e];
                    Ks[(size_t)i * ldp + j] = f2bf(m);
                    lmax = fmaxf(lmax, m);
                    lsum += m;
                }
            }
        }
    }
    for (int off = 32; off; off >>= 1) {
        lmax = fmaxf(lmax, __shfl_xor(lmax, off));
        lsum += __shfl_xor(lsum, off);
    }
    if (lane == 0) { rmax[wave] = lmax; rsum[wave] = lsum; }
    __syncthreads();
    if (tid == 0) {
        float bm = fmaxf(fmaxf(rmax[0], rmax[1]), fmaxf(rmax[2], rmax[3]));
        float bs = rsum[0] + rsum[1] + rsum[2] + rsum[3];
        atomicMax(&((unsigned int*)ws)[OFF_MAX + s], __float_as_uint(bm));
        atomicAdd(&ws[OFF_SUM + s], bs);
    }
}

// ---------------------------------------------------------------------------
// 4) Persistent cooperative Sinkhorn: K-transform, 20.5 iterations, value.
//    1024 blocks: s = b&31 (keeps each s's blocks on one XCD), chunk = b>>5.
__global__ __launch_bounds__(256, 4) void sink_kernel(float* __restrict__ ws,
                                                      const int* __restrict__ seqlen,
                                                      float* __restrict__ out) {
    cg::grid_group grid = cg::this_grid();
    const int nt = ((const int*)ws)[0], nc = ((const int*)ws)[1];
    const int R = nt + 1;
    const int ldp = ((nc + 1) + 7) & ~7;
    const int b = blockIdx.x;
    const int s = b & 31, chunk = b >> 5;
    const int tid = threadIdx.x, lane = tid & 63, wave = tid >> 6;
    const int rpc = (R + 31) >> 5;
    const int r0 = chunk * rpc;
    const int rend = min(rpc, R - r0);            // may be <= 0
    const float a_main = ws[3], a_last = ws[4];
    const float b_main = ws[5], b_last = ws[6];
    unsigned short* Kb = reinterpret_cast<unsigned short*>(ws + OFF_KF) + (size_t)s * KSLOT;
    float* u  = ws + OFF_U + s * VST;
    float* y0 = ws + OFF_Y + s * VST;
    float* y1 = ws + OFF_Y + S_MAX * VST + s * VST;

    __shared__ __align__(16) float sm[2056];
    __shared__ float wred[4];

    // ---- phase 0: M -> K transform (rows r0..r0+rend) ----
    {
        const float delta = __uint_as_float(((const unsigned int*)ws)[OFF_MAX + s]);
        const float lam = (float)nt * (float)nc / ws[OFF_SUM + s];
        const float kpad = __expf(-lam * delta) + 1e-6f;
        for (int rr = 0; rr < rend; rr++) {
            const int i = r0 + rr;
            unsigned short* row = Kb + (size_t)i * ldp;
            for (int j = tid; j < ldp; j += 256) {
                float kv;
                if (j > nc)                  kv = 0.0f;          // pad tail
                else if (i < nt && j < nc)   kv = __expf(-lam * bf2f(row[j])) + 1e-6f;
                else if (i == nt && j == nc) kv = 1.0f + 1e-6f;  // corner Mt=0
                else                         kv = kpad;          // delta pad
                row[j] = f2bf(kv);
            }
        }
    }
    grid.sync();

    for (int k = 0; k < 21; k++) {
        float* ycur = (k & 1) ? y1 : y0;
        // ---- phase A: ycur[j] += sum_{i in chunk} K[i][j] * u[i] ----
        if (rend > 0)
            for (int r = tid; r < rend; r += 256) sm[r] = u[r0 + r];
        __syncthreads();
        if (rend > 0) {
            const unsigned short* Kp = Kb + (size_t)r0 * ldp;
            for (int j = tid; j <= nc; j += 256) {
                const unsigned short* Kc = Kp + j;
                float acc = 0.0f;
                int r = 0;
                for (; r + 4 <= rend; r += 4)
                    acc += bf2f(Kc[(size_t)(r + 0) * ldp]) * sm[r + 0]
                         + bf2f(Kc[(size_t)(r + 1) * ldp]) * sm[r + 1]
                         + bf2f(Kc[(size_t)(r + 2) * ldp]) * sm[r + 2]
                         + bf2f(Kc[(size_t)(r + 3) * ldp]) * sm[r + 3];
                for (; r < rend; r++) acc += bf2f(Kc[(size_t)r * ldp]) * sm[r];
                atomicAdd(&ycur[j], acc);
            }
        }
        grid.sync();
        if (k == 20) break;

        // ---- phase B: u[i] = a_i / sum_j K[i][j] * (b_j / ycur[j]) ----
        for (int j = tid; j < ldp; j += 256)
            sm[j] = (j <= nc) ? (((j < nc) ? b_main : b_last) / ycur[j]) : 0.0f;
        __syncthreads();
        for (int rr = wave; rr < rend; rr += 4) {
            const int i = r0 + rr;
            const unsigned short* Krow = Kb + (size_t)i * ldp;
            float acc = 0.0f;
            for (int j4 = lane * 4; j4 < ldp; j4 += 256) {
                ushort4 kk = *(const ushort4*)(Krow + j4);
                float4 wv = *(const float4*)(&sm[j4]);
                acc += bf2f(kk.x) * wv.x + bf2f(kk.y) * wv.y
                     + bf2f(kk.z) * wv.z + bf2f(kk.w) * wv.w;
            }
            for (int off = 32; off; off >>= 1) acc += __shfl_xor(acc, off);
            if (lane == 0) u[i] = ((i < nt) ? a_main : a_last) / acc;
        }
        // zero the other y buffer for the next A phase
        {
            float* yoth = (k & 1) ? y0 : y1;
            const int j = chunk * 256 + tid;
            if (j < VST) yoth[j] = 0.0f;
        }
        grid.sync();
    }

    // ---- value phase: out += 2 * sum_ij u_i K_ij Mt_ij v_j  (Mt via log) ----
    {
        const float* y20 = y0;   // k=20 is even
        const float meanM = ws[OFF_SUM + s] / ((float)nt * (float)nc);
        for (int j = tid; j < ldp; j += 256)
            sm[j] = (j <= nc) ? (((j < nc) ? b_main : b_last) / y20[j]) : 0.0f;
        __syncthreads();
        float wsum = 0.0f;
        for (int rr = wave; rr < rend; rr += 4) {
            const int i = r0 + rr;
            const unsigned short* Krow = Kb + (size_t)i * ldp;
            float acc = 0.0f;
            for (int j4 = lane * 4; j4 < ldp; j4 += 256) {
                ushort4 kk = *(const ushort4*)(Krow + j4);
                float4 wv = *(const float4*)(&sm[j4]);
                float k0 = bf2f(kk.x), k1 = bf2f(kk.y), k2 = bf2f(kk.z), k3 = bf2f(kk.w);
                acc += k0 * (-__logf(fmaxf(k0 - 1e-6f, 1e-30f))) * wv.x
                     + k1 * (-__logf(fmaxf(k1 - 1e-6f, 1e-30f))) * wv.y
                     + k2 * (-__logf(fmaxf(k2 - 1e-6f, 1e-30f))) * wv.z
                     + k3 * (-__logf(fmaxf(k3 - 1e-6f, 1e-30f))) * wv.w;
            }
            acc *= meanM;
            for (int off = 32; off; off >>= 1) acc += __shfl_xor(acc, off);
            wsum += u[i] * acc;
        }
        if (lane == 0) wred[wave] = wsum;
        __syncthreads();
        if (tid == 0 && s < *seqlen)
            atomicAdd(out, 2.0f * (wred[0] + wred[1] + wred[2] + wred[3]));
    }
}

// ---------------------------------------------------------------------------
extern "C" void kernel_launch(void* const* d_in, const int* in_sizes, int n_in,
                              void* d_out, int out_size, void* d_ws, size_t ws_size,
                              hipStream_t stream) {
    const float* enc  = (const float*)d_in[0];
    const int* seqlen = (const int*)d_in[1];
    const int* t      = (const int*)d_in[2];
    float* out = (float*)d_out;
    float* ws  = (float*)d_ws;

    hipMemsetAsync(d_out, 0, sizeof(float), stream);
    hipMemsetAsync(d_ws, 0, (size_t)OFF_KF * sizeof(float), stream);   // ~1.07 MB base region

    idx_kernel <<<1, 1024, 0, stream>>>(t, ws);
    norm_kernel<<<16384, 256, 0, stream>>>(enc, ws);
    m_kernel   <<<dim3(32, 32, 32), 256, 0, stream>>>(enc, ws);

    float* wsp = ws;
    const int* slp = seqlen;
    float* outp = out;
    void* args[3] = { (void*)&wsp, (void*)&slp, (void*)&outp };
    hipLaunchCooperativeKernel((void*)sink_kernel, dim3(1024), dim3(256), args, 0, stream);
}

// Round 4
// 2183.580 us; speedup vs baseline: 2.8531x; 2.8531x over previous
//
#include <hip/hip_runtime.h>
#include <hip/hip_bf16.h>

// ---------------- workspace layout (float-element offsets) ----------------
#define S_MAX 32
#define VST   2052                    // per-s vector stride (covers nt+1 <= 2048)
#define KSLOT 1057824                 // bf16 elems per s slot >= max (nt+1)*ldp
#define NCHUNK 64                     // row-chunks per s in the Sinkhorn phases

#define OFF_MAX  64                   // 32 uints (float bits, atomicMax of M)
#define OFF_SUM  96                   // 32 floats (atomicAdd of sum M)
#define OFF_IT   128                  // int[2048] treated indices
#define OFF_IC   2176                 // int[2048] control indices
#define OFF_NORM 4352                 // float[32][2048] row sq-norms -> ends 69888
#define OFF_U    69888                // float[32][VST] current u -> ends 135552
#define OFF_Y    135552               // 2 x 32 x VST y double-buffer -> ends 266880
#define OFF_KF   266880               // bf16 K region; 32*KSLOT ushorts (~64.6 MB)
// total ws usage: 266880*4 + 32*KSLOT*2 = 68,768,256 bytes (~65.6 MiB)

typedef __attribute__((ext_vector_type(8))) short bf16x8;
typedef __attribute__((ext_vector_type(4))) float f32x4;

__device__ __forceinline__ float bf2f(unsigned short u) {
    return __uint_as_float(((unsigned)u) << 16);
}
__device__ __forceinline__ float bflo(unsigned u) { return __uint_as_float(u << 16); }
__device__ __forceinline__ float bfhi(unsigned u) { return __uint_as_float(u & 0xffff0000u); }
__device__ __forceinline__ unsigned short f2bf(float f) {
    __hip_bfloat16 h = __float2bfloat16(f);
    return *reinterpret_cast<unsigned short*>(&h);
}
__device__ __forceinline__ bf16x8 cvt8(const float* __restrict__ p) {
    const float4 lo = *(const float4*)p;
    const float4 hi = *(const float4*)(p + 4);
    bf16x8 r;
    r[0] = (short)f2bf(lo.x); r[1] = (short)f2bf(lo.y);
    r[2] = (short)f2bf(lo.z); r[3] = (short)f2bf(lo.w);
    r[4] = (short)f2bf(hi.x); r[5] = (short)f2bf(hi.y);
    r[6] = (short)f2bf(hi.z); r[7] = (short)f2bf(hi.w);
    return r;
}

// ---------------------------------------------------------------------------
// 1) index compaction + meta + u0 = a  (one block)
__global__ __launch_bounds__(1024) void idx_kernel(const int* __restrict__ t, float* __restrict__ ws) {
    __shared__ int sc[2048];
    const int tid = threadIdx.x;
    int p0 = (t[tid] > 0) ? 1 : 0;
    int p1 = (t[tid + 1024] > 0) ? 1 : 0;
    sc[tid] = p0; sc[tid + 1024] = p1;
    __syncthreads();
    for (int off = 1; off < 2048; off <<= 1) {
        int v0 = 0, v1 = 0;
        if (tid >= off)        v0 = sc[tid - off];
        if (tid + 1024 >= off) v1 = sc[tid + 1024 - off];
        __syncthreads();
        sc[tid] += v0; sc[tid + 1024] += v1;
        __syncthreads();
    }
    const int incl0 = sc[tid], incl1 = sc[tid + 1024];
    const int nt = sc[2047];
    const int nc = 2048 - nt;
    int* itl = (int*)(ws + OFF_IT);
    int* icl = (int*)(ws + OFF_IC);
    if (p0) itl[incl0 - 1] = tid;        else icl[tid - incl0] = tid;
    if (p1) itl[incl1 - 1] = tid + 1024; else icl[tid + 1024 - incl1] = tid + 1024;

    const float p = (float)nt / 2048.0f;
    const float a_main = p / (float)nt;
    const float a_last = 1.0f - p;
    if (tid == 0) {
        ((int*)ws)[0] = nt;
        ((int*)ws)[1] = nc;
        ws[2] = p;
        ws[3] = a_main;
        ws[4] = a_last;
        ws[5] = (1.0f - p) / (float)nc;   // b_main
        ws[6] = p;                        // b_last
    }
    for (int s = 0; s < S_MAX; s++) {
        float* u = ws + OFF_U + s * VST;
        for (int i = tid; i < VST; i += 1024)
            u[i] = (i < nt) ? a_main : ((i == nt) ? a_last : 0.0f);
    }
}

// ---------------------------------------------------------------------------
// 2) row squared norms: one wave per (n,s) row of 256 floats
__global__ __launch_bounds__(256) void norm_kernel(const float* __restrict__ enc, float* __restrict__ ws) {
    const int gw = blockIdx.x * 4 + (threadIdx.x >> 6);
    const int lane = threadIdx.x & 63;
    const int n = gw >> 5, s = gw & 31;
    const float4* row = (const float4*)(enc + ((size_t)n * 32 + s) * 256);
    float4 v = row[lane];
    float ss = v.x * v.x + v.y * v.y + v.z * v.z + v.w * v.w;
    for (int off = 32; off; off >>= 1) ss += __shfl_xor(ss, off);
    if (lane == 0) ws[OFF_NORM + s * 2048 + n] = ss;
}

// ---------------------------------------------------------------------------
// 3) M tiles via MFMA bf16 (64x64/block, 4 waves x 2x2 frags of 16x16x32)
__global__ __launch_bounds__(256) void m_kernel(const float* __restrict__ enc, float* __restrict__ ws) {
    const int s = blockIdx.z;
    const int nt = ((const int*)ws)[0], nc = ((const int*)ws)[1];
    const int ibase = blockIdx.y * 64, jbase = blockIdx.x * 64;
    if (ibase >= nt || jbase >= nc) return;
    const int ldp = ((nc + 1) + 7) & ~7;

    __shared__ int ridx[64], cidx[64];
    __shared__ float nrmA[64], nrmB[64];
    __shared__ float rmax[4], rsum[4];

    const int tid = threadIdx.x;
    const int* itl = (const int*)(ws + OFF_IT);
    const int* icl = (const int*)(ws + OFF_IC);
    if (tid < 64) {
        int i = ibase + tid;
        int g = itl[(i < nt) ? i : (nt - 1)];
        ridx[tid] = g;
        nrmA[tid] = ws[OFF_NORM + s * 2048 + g];
    } else if (tid < 128) {
        int j = jbase + (tid - 64);
        int g = icl[(j < nc) ? j : (nc - 1)];
        cidx[tid - 64] = g;
        nrmB[tid - 64] = ws[OFF_NORM + s * 2048 + g];
    }
    __syncthreads();

    const int lane = tid & 63, wave = tid >> 6;
    const int wr = wave >> 1, wc = wave & 1;
    const int row16 = lane & 15, koff = (lane >> 4) * 8;
    const int ar0 = wr * 32 + row16;
    const int bc0 = wc * 32 + row16;

    const float* pa0 = enc + ((size_t)ridx[ar0]      * 32 + s) * 256 + koff;
    const float* pa1 = enc + ((size_t)ridx[ar0 + 16] * 32 + s) * 256 + koff;
    const float* pb0 = enc + ((size_t)cidx[bc0]      * 32 + s) * 256 + koff;
    const float* pb1 = enc + ((size_t)cidx[bc0 + 16] * 32 + s) * 256 + koff;

    f32x4 acc00 = {0.f,0.f,0.f,0.f}, acc01 = {0.f,0.f,0.f,0.f};
    f32x4 acc10 = {0.f,0.f,0.f,0.f}, acc11 = {0.f,0.f,0.f,0.f};
    #pragma unroll
    for (int d0 = 0; d0 < 256; d0 += 32) {
        bf16x8 a0 = cvt8(pa0 + d0), a1 = cvt8(pa1 + d0);
        bf16x8 b0 = cvt8(pb0 + d0), b1 = cvt8(pb1 + d0);
        acc00 = __builtin_amdgcn_mfma_f32_16x16x32_bf16(a0, b0, acc00, 0, 0, 0);
        acc01 = __builtin_amdgcn_mfma_f32_16x16x32_bf16(a0, b1, acc01, 0, 0, 0);
        acc10 = __builtin_amdgcn_mfma_f32_16x16x32_bf16(a1, b0, acc10, 0, 0, 0);
        acc11 = __builtin_amdgcn_mfma_f32_16x16x32_bf16(a1, b1, acc11, 0, 0, 0);
    }

    // C/D layout: col = lane&15, row = (lane>>4)*4 + e
    unsigned short* Ks = reinterpret_cast<unsigned short*>(ws + OFF_KF) + (size_t)s * KSLOT;
    const int crow = (lane >> 4) * 4;
    const int ccol = lane & 15;
    float lmax = 0.0f, lsum = 0.0f;
    #pragma unroll
    for (int fi = 0; fi < 2; fi++) {
        #pragma unroll
        for (int fj = 0; fj < 2; fj++) {
            f32x4 a = (fi == 0) ? ((fj == 0) ? acc00 : acc01)
                                : ((fj == 0) ? acc10 : acc11);
            #pragma unroll
            for (int e = 0; e < 4; e++) {
                const int ti = wr * 32 + fi * 16 + crow + e;
                const int tj = wc * 32 + fj * 16 + ccol;
                const int i = ibase + ti, j = jbase + tj;
                if (i < nt && j < nc) {
                    float m = nrmA[ti] + nrmB[tj] - 2.0f * a[e];
                    Ks[(size_t)i * ldp + j] = f2bf(m);
                    lmax = fmaxf(lmax, m);
                    lsum += m;
                }
            }
        }
    }
    for (int off = 32; off; off >>= 1) {
        lmax = fmaxf(lmax, __shfl_xor(lmax, off));
        lsum += __shfl_xor(lsum, off);
    }
    if (lane == 0) { rmax[wave] = lmax; rsum[wave] = lsum; }
    __syncthreads();
    if (tid == 0) {
        float bm = fmaxf(fmaxf(rmax[0], rmax[1]), fmaxf(rmax[2], rmax[3]));
        float bs = rsum[0] + rsum[1] + rsum[2] + rsum[3];
        atomicMax(&((unsigned int*)ws)[OFF_MAX + s], __float_as_uint(bm));
        atomicAdd(&ws[OFF_SUM + s], bs);
    }
}

// ---------------------------------------------------------------------------
// 4) phase A (row-major): y[k&1][j] += sum_{i in chunk} K[i][j] * u[i]
//    TR variant additionally transforms M -> K in place (iteration 0 only).
//    Grid: (NCHUNK, 32).  Thread owns 4 consecutive j; uint2 (8B) K loads.
template<bool TR>
__global__ __launch_bounds__(256) void phaseA_t(float* __restrict__ ws, int k) {
    const int s = blockIdx.y, chunk = blockIdx.x;
    const int nt = ((const int*)ws)[0], nc = ((const int*)ws)[1];
    const int R = nt + 1;
    const int ldp = ((nc + 1) + 7) & ~7;
    const int rpc = (R + NCHUNK - 1) / NCHUNK;
    const int r0 = chunk * rpc;
    const int rend = min(rpc, R - r0);
    if (rend <= 0) return;

    const float* u = ws + OFF_U + s * VST;
    float* y = ws + OFF_Y + (size_t)(k & 1) * S_MAX * VST + s * VST;
    unsigned short* Kb = reinterpret_cast<unsigned short*>(ws + OFF_KF) + (size_t)s * KSLOT;

    __shared__ float u_l[40];
    const int tid = threadIdx.x;
    for (int r = tid; r < rend; r += 256) u_l[r] = u[r0 + r];
    __syncthreads();

    float lam = 0.f, kpad = 0.f;
    if (TR) {
        const float delta = __uint_as_float(((const unsigned int*)ws)[OFF_MAX + s]);
        lam = (float)nt * (float)nc / ws[OFF_SUM + s];
        kpad = __expf(-lam * delta) + 1e-6f;
    }

    for (int j0 = tid * 4; j0 < ldp; j0 += 1024) {
        float a0 = 0.f, a1 = 0.f, a2 = 0.f, a3 = 0.f;
        unsigned short* Kpj = Kb + (size_t)r0 * ldp + j0;
        #pragma unroll 4
        for (int r = 0; r < rend; r++) {
            const float uv = u_l[r];
            uint2 kk = *reinterpret_cast<uint2*>(Kpj + (size_t)r * ldp);
            float k0, k1, k2, k3;
            if (TR) {
                const int i = r0 + r;
                const float m0 = bflo(kk.x), m1 = bfhi(kk.x);
                const float m2 = bflo(kk.y), m3 = bfhi(kk.y);
                k0 = (j0+0 > nc) ? 0.f : ((i == nt) ? ((j0+0 == nc) ? 1.0f+1e-6f : kpad)
                       : ((j0+0 == nc) ? kpad : __expf(-lam * m0) + 1e-6f));
                k1 = (j0+1 > nc) ? 0.f : ((i == nt) ? ((j0+1 == nc) ? 1.0f+1e-6f : kpad)
                       : ((j0+1 == nc) ? kpad : __expf(-lam * m1) + 1e-6f));
                k2 = (j0+2 > nc) ? 0.f : ((i == nt) ? ((j0+2 == nc) ? 1.0f+1e-6f : kpad)
                       : ((j0+2 == nc) ? kpad : __expf(-lam * m2) + 1e-6f));
                k3 = (j0+3 > nc) ? 0.f : ((i == nt) ? ((j0+3 == nc) ? 1.0f+1e-6f : kpad)
                       : ((j0+3 == nc) ? kpad : __expf(-lam * m3) + 1e-6f));
                uint2 pk;
                pk.x = (unsigned)f2bf(k0) | ((unsigned)f2bf(k1) << 16);
                pk.y = (unsigned)f2bf(k2) | ((unsigned)f2bf(k3) << 16);
                *reinterpret_cast<uint2*>(Kpj + (size_t)r * ldp) = pk;
            } else {
                k0 = bflo(kk.x); k1 = bfhi(kk.x);
                k2 = bflo(kk.y); k3 = bfhi(kk.y);
            }
            a0 += k0 * uv; a1 += k1 * uv; a2 += k2 * uv; a3 += k3 * uv;
        }
        if (j0 + 3 <= nc) {
            atomicAdd(&y[j0+0], a0); atomicAdd(&y[j0+1], a1);
            atomicAdd(&y[j0+2], a2); atomicAdd(&y[j0+3], a3);
        } else {
            if (j0+0 <= nc) atomicAdd(&y[j0+0], a0);
            if (j0+1 <= nc) atomicAdd(&y[j0+1], a1);
            if (j0+2 <= nc) atomicAdd(&y[j0+2], a2);
            if (j0+3 <= nc) atomicAdd(&y[j0+3], a3);
        }
    }
}

// ---------------------------------------------------------------------------
// 5) phase B: u[i] = a_i / sum_j K[i][j] * (b_j / y[k&1][j]); zero y[(k+1)&1]
__global__ __launch_bounds__(256) void phaseB_kernel(float* __restrict__ ws, int k) {
    const int s = blockIdx.y, chunk = blockIdx.x;
    const int nt = ((const int*)ws)[0], nc = ((const int*)ws)[1];
    const int R = nt + 1;
    const int ldp = ((nc + 1) + 7) & ~7;
    const int rpc = (R + NCHUNK - 1) / NCHUNK;
    const int r0 = chunk * rpc;
    const int rend = min(rpc, R - r0);
    const float a_main = ws[3], a_last = ws[4];
    const float b_main = ws[5], b_last = ws[6];
    const float* ycur = ws + OFF_Y + (size_t)(k & 1) * S_MAX * VST + s * VST;
    float* ynext     = ws + OFF_Y + (size_t)((k + 1) & 1) * S_MAX * VST + s * VST;
    float* u = ws + OFF_U + s * VST;
    const int tid = threadIdx.x, lane = tid & 63, wave = tid >> 6;

    // zero next y buffer (each (chunk,tid) owns disjoint slots; done before A(k+1) launch)
    { int j = chunk * 256 + tid; if (j < VST) ynext[j] = 0.0f; }

    __shared__ __align__(16) float w_l[2056];
    for (int j = tid; j < 2056; j += 256)
        w_l[j] = (j <= nc) ? (((j < nc) ? b_main : b_last) / ycur[j]) : 0.0f;
    __syncthreads();
    if (rend <= 0) return;

    const unsigned short* Kb = reinterpret_cast<const unsigned short*>(ws + OFF_KF) + (size_t)s * KSLOT;
    for (int rr = wave; rr < rend; rr += 4) {
        const int i = r0 + rr;
        const unsigned short* Krow = Kb + (size_t)i * ldp;
        float acc = 0.0f;
        for (int j8 = lane * 8; j8 < ldp; j8 += 512) {
            uint4 kk = *reinterpret_cast<const uint4*>(Krow + j8);
            float4 w0 = *reinterpret_cast<const float4*>(&w_l[j8]);
            float4 w1 = *reinterpret_cast<const float4*>(&w_l[j8 + 4]);
            acc += bflo(kk.x) * w0.x + bfhi(kk.x) * w0.y
                 + bflo(kk.y) * w0.z + bfhi(kk.y) * w0.w
                 + bflo(kk.z) * w1.x + bfhi(kk.z) * w1.y
                 + bflo(kk.w) * w1.z + bfhi(kk.w) * w1.w;
        }
        for (int off = 32; off; off >>= 1) acc += __shfl_xor(acc, off);
        if (lane == 0) u[i] = ((i < nt) ? a_main : a_last) / acc;
    }
}

// ---------------------------------------------------------------------------
// 6) value: out += 2 * sum_ij u_i K_ij Mt_ij v_j  (Mt via log recovery)
__global__ __launch_bounds__(256) void value_kernel(float* __restrict__ ws, const int* __restrict__ seqlen,
                                                    float* __restrict__ out) {
    const int s = blockIdx.y, chunk = blockIdx.x;
    if (s >= *seqlen) return;
    const int nt = ((const int*)ws)[0], nc = ((const int*)ws)[1];
    const int R = nt + 1;
    const int ldp = ((nc + 1) + 7) & ~7;
    const int rpc = (R + NCHUNK - 1) / NCHUNK;
    const int r0 = chunk * rpc;
    const int rend = min(rpc, R - r0);
    if (rend <= 0) return;
    const float b_main = ws[5], b_last = ws[6];
    const float meanM = ws[OFF_SUM + s] / ((float)nt * (float)nc);   // 1/lam
    const float* y20 = ws + OFF_Y + s * VST;                          // k=20 even -> buf0
    const float* u   = ws + OFF_U + s * VST;
    const int tid = threadIdx.x, lane = tid & 63, wave = tid >> 6;

    __shared__ __align__(16) float w_l[2056];
    __shared__ float wred[4];
    for (int j = tid; j < 2056; j += 256)
        w_l[j] = (j <= nc) ? (((j < nc) ? b_main : b_last) / y20[j]) : 0.0f;
    __syncthreads();

    const unsigned short* Kb = reinterpret_cast<const unsigned short*>(ws + OFF_KF) + (size_t)s * KSLOT;
    float wsum = 0.0f;
    for (int rr = wave; rr < rend; rr += 4) {
        const int i = r0 + rr;
        const unsigned short* Krow = Kb + (size_t)i * ldp;
        float acc = 0.0f;
        for (int j8 = lane * 8; j8 < ldp; j8 += 512) {
            uint4 kk = *reinterpret_cast<const uint4*>(Krow + j8);
            float4 w0 = *reinterpret_cast<const float4*>(&w_l[j8]);
            float4 w1 = *reinterpret_cast<const float4*>(&w_l[j8 + 4]);
            float k0 = bflo(kk.x), k1 = bfhi(kk.x), k2 = bflo(kk.y), k3 = bfhi(kk.y);
            float k4 = bflo(kk.z), k5 = bfhi(kk.z), k6 = bflo(kk.w), k7 = bfhi(kk.w);
            acc += k0 * (-__logf(fmaxf(k0 - 1e-6f, 1e-30f))) * w0.x
                 + k1 * (-__logf(fmaxf(k1 - 1e-6f, 1e-30f))) * w0.y
                 + k2 * (-__logf(fmaxf(k2 - 1e-6f, 1e-30f))) * w0.z
                 + k3 * (-__logf(fmaxf(k3 - 1e-6f, 1e-30f))) * w0.w
                 + k4 * (-__logf(fmaxf(k4 - 1e-6f, 1e-30f))) * w1.x
                 + k5 * (-__logf(fmaxf(k5 - 1e-6f, 1e-30f))) * w1.y
                 + k6 * (-__logf(fmaxf(k6 - 1e-6f, 1e-30f))) * w1.z
                 + k7 * (-__logf(fmaxf(k7 - 1e-6f, 1e-30f))) * w1.w;
        }
        acc *= meanM;
        for (int off = 32; off; off >>= 1) acc += __shfl_xor(acc, off);
        wsum += u[i] * acc;
    }
    if (lane == 0) wred[wave] = wsum;
    __syncthreads();
    if (tid == 0)
        atomicAdd(out, 2.0f * (wred[0] + wred[1] + wred[2] + wred[3]));
}

// ---------------------------------------------------------------------------
extern "C" void kernel_launch(void* const* d_in, const int* in_sizes, int n_in,
                              void* d_out, int out_size, void* d_ws, size_t ws_size,
                              hipStream_t stream) {
    const float* enc  = (const float*)d_in[0];
    const int* seqlen = (const int*)d_in[1];
    const int* t      = (const int*)d_in[2];
    float* out = (float*)d_out;
    float* ws  = (float*)d_ws;

    hipMemsetAsync(d_out, 0, sizeof(float), stream);
    hipMemsetAsync(d_ws, 0, (size_t)OFF_KF * sizeof(float), stream);   // ~1.07 MB base region

    idx_kernel <<<1, 1024, 0, stream>>>(t, ws);
    norm_kernel<<<16384, 256, 0, stream>>>(enc, ws);
    m_kernel   <<<dim3(32, 32, 32), 256, 0, stream>>>(enc, ws);

    const dim3 pg(NCHUNK, 32);
    phaseA_t<true><<<pg, 256, 0, stream>>>(ws, 0);   // fused M->K transform + A(0)
    phaseB_kernel<<<pg, 256, 0, stream>>>(ws, 0);
    for (int k = 1; k < 20; k++) {
        phaseA_t<false><<<pg, 256, 0, stream>>>(ws, k);
        phaseB_kernel<<<pg, 256, 0, stream>>>(ws, k);
    }
    phaseA_t<false><<<pg, 256, 0, stream>>>(ws, 20);
    value_kernel<<<pg, 256, 0, stream>>>(ws, seqlen, out);
}

// Round 5
// 1669.497 us; speedup vs baseline: 3.7316x; 1.3079x over previous
//
#include <hip/hip_runtime.h>
#include <hip/hip_bf16.h>

// ---------------- workspace layout (float-element offsets) ----------------
#define S_MAX 32
#define VST   2052                    // per-s vector stride (covers nt+1 <= 2048)
#define KSLOT 1060864                 // bf16 elems per s K slot: max (nt+1)*ldp + 2048 pad
#define NCHUNK 64                     // row-chunks per s in the Sinkhorn phases

#define OFF_MAX  64                   // 32 uints (float bits, atomicMax of M)
#define OFF_SUM  96                   // 32 floats (atomicAdd of sum M)
#define OFF_RNK  128                  // int[2048]: pool destination row per sample
#define OFF_NORM 2176                 // float[32][2048] sq-norms by pool row -> ends 67712
#define OFF_U    67712                // float[32][VST] u vector -> ends 133376
#define OFF_Y    133376               // 3 x 32 x VST y triple-buffer -> ends 330368
#define OFF_POOL 330368               // bf16 pool Xall[32][2048][256] -> 8,388,608 floats -> ends 8,718,976
#define OFF_KF   8718976              // bf16 K region; 32*KSLOT ushorts (~64.8 MB)
// total ws usage: (8718976 + 16973824) * 4 = 102,771,200 bytes (~98 MiB)

typedef __attribute__((ext_vector_type(8))) short bf16x8;
typedef __attribute__((ext_vector_type(4))) float f32x4;

__device__ __forceinline__ float bflo(unsigned u) { return __uint_as_float(u << 16); }
__device__ __forceinline__ float bfhi(unsigned u) { return __uint_as_float(u & 0xffff0000u); }
__device__ __forceinline__ unsigned short f2bf(float f) {
    __hip_bfloat16 h = __float2bfloat16(f);
    return *reinterpret_cast<unsigned short*>(&h);
}

// ---------------------------------------------------------------------------
// 1) index scan -> pool destination row + meta + u0 = a  (one block)
__global__ __launch_bounds__(1024) void idx_kernel(const int* __restrict__ t, float* __restrict__ ws) {
    __shared__ int sc[2048];
    const int tid = threadIdx.x;
    int p0 = (t[tid] > 0) ? 1 : 0;
    int p1 = (t[tid + 1024] > 0) ? 1 : 0;
    sc[tid] = p0; sc[tid + 1024] = p1;
    __syncthreads();
    for (int off = 1; off < 2048; off <<= 1) {
        int v0 = 0, v1 = 0;
        if (tid >= off)        v0 = sc[tid - off];
        if (tid + 1024 >= off) v1 = sc[tid + 1024 - off];
        __syncthreads();
        sc[tid] += v0; sc[tid + 1024] += v1;
        __syncthreads();
    }
    const int incl0 = sc[tid], incl1 = sc[tid + 1024];
    const int nt = sc[2047];
    const int nc = 2048 - nt;
    int* dst = (int*)(ws + OFF_RNK);
    // treated ranks from front, control ranks from the back (pool row = 2047 - rank_c)
    dst[tid]        = p0 ? (incl0 - 1) : (2047 - (tid - incl0));
    dst[tid + 1024] = p1 ? (incl1 - 1) : (2047 - (tid + 1024 - incl1));

    const float p = (float)nt / 2048.0f;
    const float a_main = p / (float)nt;
    const float a_last = 1.0f - p;
    if (tid == 0) {
        ((int*)ws)[0] = nt;
        ((int*)ws)[1] = nc;
        ws[2] = p;
        ws[3] = a_main;
        ws[4] = a_last;
        ws[5] = (1.0f - p) / (float)nc;   // b_main
        ws[6] = p;                        // b_last
    }
    for (int s = 0; s < S_MAX; s++) {
        float* u = ws + OFF_U + s * VST;
        for (int i = tid; i < VST; i += 1024)
            u[i] = (i < nt) ? a_main : ((i == nt) ? a_last : 0.0f);
    }
}

// ---------------------------------------------------------------------------
// 2) compact + cast: gather (n,s) row -> bf16 pool row dst[n]; fused sq-norm
__global__ __launch_bounds__(256) void compact_kernel(const float* __restrict__ enc, float* __restrict__ ws) {
    const int gw = blockIdx.x * 4 + (threadIdx.x >> 6);   // 0..65535
    const int lane = threadIdx.x & 63;
    const int n = gw >> 5, s = gw & 31;
    const int r = ((const int*)(ws + OFF_RNK))[n];
    const float4 v = *(const float4*)(enc + ((size_t)n * 32 + s) * 256 + lane * 4);
    float ss = v.x * v.x + v.y * v.y + v.z * v.z + v.w * v.w;
    for (int off = 32; off; off >>= 1) ss += __shfl_xor(ss, off);
    unsigned short* pool = reinterpret_cast<unsigned short*>(ws + OFF_POOL);
    ushort4 pk = { f2bf(v.x), f2bf(v.y), f2bf(v.z), f2bf(v.w) };
    *reinterpret_cast<ushort4*>(pool + ((size_t)(s * 2048 + r)) * 256 + lane * 4) = pk;
    if (lane == 0) ws[OFF_NORM + s * 2048 + r] = ss;
}

// ---------------------------------------------------------------------------
// 3) M tiles via MFMA bf16 from compact pool: 128x128/block, 4 waves (2x2),
//    each wave 64x64 = 4x4 frags of 16x16x32.
__global__ __launch_bounds__(256) void m_kernel(float* __restrict__ ws) {
    const int s = blockIdx.z;
    const int nt = ((const int*)ws)[0], nc = ((const int*)ws)[1];
    const int ibase = blockIdx.y * 128, jbase = blockIdx.x * 128;
    if (ibase >= nt || jbase >= nc) return;
    const int ldp = ((nc + 1) + 7) & ~7;

    __shared__ float nrmA[128], nrmB[128];
    __shared__ float rmax[4], rsum[4];
    const int tid = threadIdx.x;
    if (tid < 128) {
        nrmA[tid] = ws[OFF_NORM + s * 2048 + (ibase + tid)];
    } else {
        const int j = jbase + (tid - 128);
        nrmB[tid - 128] = ws[OFF_NORM + s * 2048 + (2047 - j)];
    }
    __syncthreads();

    const int lane = tid & 63, wave = tid >> 6;
    const int wr = wave >> 1, wc = wave & 1;
    const int row16 = lane & 15, koff = (lane >> 4) * 8;
    const unsigned short* pool = reinterpret_cast<const unsigned short*>(ws + OFF_POOL);
    const size_t sbase = (size_t)s * 2048 * 256;

    f32x4 acc[4][4] = {};
    #pragma unroll
    for (int d0 = 0; d0 < 256; d0 += 32) {
        bf16x8 af[4], bg[4];
        #pragma unroll
        for (int f = 0; f < 4; f++) {
            const int ar = ibase + wr * 64 + f * 16 + row16;           // pool row (A)
            const int br = 2047 - (jbase + wc * 64 + f * 16 + row16);  // pool row (B)
            af[f] = *(const bf16x8*)(pool + sbase + (size_t)ar * 256 + koff + d0);
            bg[f] = *(const bf16x8*)(pool + sbase + (size_t)br * 256 + koff + d0);
        }
        #pragma unroll
        for (int fi = 0; fi < 4; fi++)
            #pragma unroll
            for (int fj = 0; fj < 4; fj++)
                acc[fi][fj] = __builtin_amdgcn_mfma_f32_16x16x32_bf16(af[fi], bg[fj], acc[fi][fj], 0, 0, 0);
    }

    // C/D layout: col = lane&15, row = (lane>>4)*4 + e
    unsigned short* Ks = reinterpret_cast<unsigned short*>(ws + OFF_KF) + (size_t)s * KSLOT;
    const int crow = (lane >> 4) * 4, ccol = lane & 15;
    float lmax = 0.0f, lsum = 0.0f;
    #pragma unroll
    for (int fi = 0; fi < 4; fi++) {
        #pragma unroll
        for (int fj = 0; fj < 4; fj++) {
            #pragma unroll
            for (int e = 0; e < 4; e++) {
                const int ti = wr * 64 + fi * 16 + crow + e;
                const int tj = wc * 64 + fj * 16 + ccol;
                const int i = ibase + ti, j = jbase + tj;
                if (i < nt && j < nc) {
                    float m = nrmA[ti] + nrmB[tj] - 2.0f * acc[fi][fj][e];
                    Ks[(size_t)i * ldp + j] = f2bf(m);
                    lmax = fmaxf(lmax, m);
                    lsum += m;
                }
            }
        }
    }
    for (int off = 32; off; off >>= 1) {
        lmax = fmaxf(lmax, __shfl_xor(lmax, off));
        lsum += __shfl_xor(lsum, off);
    }
    if (lane == 0) { rmax[wave] = lmax; rsum[wave] = lsum; }
    __syncthreads();
    if (tid == 0) {
        float bm = fmaxf(fmaxf(rmax[0], rmax[1]), fmaxf(rmax[2], rmax[3]));
        float bs = rsum[0] + rsum[1] + rsum[2] + rsum[3];
        atomicMax(&((unsigned int*)ws)[OFF_MAX + s], __float_as_uint(bm));
        atomicAdd(&ws[OFF_SUM + s], bs);
    }
}

// ---------------------------------------------------------------------------
// 4) A0 + M->K transform: y0[j] += sum_i K[i][j]*a_i, K computed in place.
//    Thread owns 8 consecutive j (uint4); wave streams 1KB/row.
__global__ __launch_bounds__(256) void phaseA0_kernel(float* __restrict__ ws) {
    const int s = blockIdx.y, chunk = blockIdx.x;
    const int nt = ((const int*)ws)[0], nc = ((const int*)ws)[1];
    const int R = nt + 1;
    const int ldp = ((nc + 1) + 7) & ~7;
    const int rpc = (R + NCHUNK - 1) / NCHUNK;
    const int r0 = chunk * rpc;
    const int rend = min(rpc, R - r0);
    if (rend <= 0) return;
    const int j0 = threadIdx.x * 8;
    if (j0 >= ldp) return;

    const float a_main = ws[3], a_last = ws[4];
    const float delta = __uint_as_float(((const unsigned int*)ws)[OFF_MAX + s]);
    const float lam = (float)nt * (float)nc / ws[OFF_SUM + s];
    const float kpad = __expf(-lam * delta) + 1e-6f;
    float* y = ws + OFF_Y + s * VST;    // buffer 0
    unsigned short* Kb = reinterpret_cast<unsigned short*>(ws + OFF_KF) + (size_t)s * KSLOT;

    float acc[8];
    #pragma unroll
    for (int e = 0; e < 8; e++) acc[e] = 0.0f;

    for (int r = 0; r < rend; r++) {
        const int i = r0 + r;
        unsigned short* Krow = Kb + (size_t)i * ldp + j0;
        uint4 kk = *reinterpret_cast<const uint4*>(Krow);
        float mv[8] = { bflo(kk.x), bfhi(kk.x), bflo(kk.y), bfhi(kk.y),
                        bflo(kk.z), bfhi(kk.z), bflo(kk.w), bfhi(kk.w) };
        const float uv = (i < nt) ? a_main : a_last;
        unsigned short pk[8];
        #pragma unroll
        for (int e = 0; e < 8; e++) {
            const int j = j0 + e;
            float kv;
            if (j > nc)                  kv = 0.0f;
            else if (i == nt)            kv = (j == nc) ? (1.0f + 1e-6f) : kpad;
            else if (j == nc)            kv = kpad;
            else                         kv = __expf(-lam * mv[e]) + 1e-6f;
            pk[e] = f2bf(kv);
            acc[e] += kv * uv;
        }
        uint4 st;
        st.x = (unsigned)pk[0] | ((unsigned)pk[1] << 16);
        st.y = (unsigned)pk[2] | ((unsigned)pk[3] << 16);
        st.z = (unsigned)pk[4] | ((unsigned)pk[5] << 16);
        st.w = (unsigned)pk[6] | ((unsigned)pk[7] << 16);
        *reinterpret_cast<uint4*>(Krow) = st;
    }
    #pragma unroll
    for (int e = 0; e < 8; e++)
        if (j0 + e <= nc) atomicAdd(&y[j0 + e], acc[e]);
}

// ---------------------------------------------------------------------------
// 5) fused B(k)+A(k+1): per chunk-row, load K row tiles to registers ONCE;
//    dot -> u_i -> reuse registers for y' accumulation (LDS merge, one
//    global atomic per column). Triple-buffered y.
__global__ __launch_bounds__(256) void fusedBA_kernel(float* __restrict__ ws, int k) {
    const int s = blockIdx.y, chunk = blockIdx.x;
    const int nt = ((const int*)ws)[0], nc = ((const int*)ws)[1];
    const int R = nt + 1;
    const int ldp = ((nc + 1) + 7) & ~7;
    const int rpc = (R + NCHUNK - 1) / NCHUNK;
    const int r0 = chunk * rpc;
    const int rend = min(rpc, R - r0);
    const int tid = threadIdx.x, lane = tid & 63, wave = tid >> 6;

    float* ycur = ws + OFF_Y + (size_t)(k % 3) * (S_MAX * VST) + s * VST;
    float* ynxt = ws + OFF_Y + (size_t)((k + 1) % 3) * (S_MAX * VST) + s * VST;
    float* yzro = ws + OFF_Y + (size_t)((k + 2) % 3) * (S_MAX * VST) + s * VST;
    // zero the buffer for the NEXT fused kernel's A-accumulation
    { const int jz = chunk * 256 + tid; if (jz < VST) yzro[jz] = 0.0f; }

    const float a_main = ws[3], a_last = ws[4];
    const float b_main = ws[5], b_last = ws[6];

    __shared__ __align__(16) float w_l[2056];
    __shared__ float ypart[2056];
    for (int j = tid; j < 2056; j += 256) {
        w_l[j] = (j <= nc) ? (((j < nc) ? b_main : b_last) / ycur[j]) : 0.0f;
        ypart[j] = 0.0f;
    }
    __syncthreads();

    const unsigned short* Kb = reinterpret_cast<const unsigned short*>(ws + OFF_KF) + (size_t)s * KSLOT;
    float* u = ws + OFF_U + s * VST;

    float va[4][8];
    #pragma unroll
    for (int t = 0; t < 4; t++)
        #pragma unroll
        for (int e = 0; e < 8; e++) va[t][e] = 0.0f;

    for (int rr = wave; rr < rend; rr += 4) {
        const int i = r0 + rr;
        const unsigned short* Krow = Kb + (size_t)i * ldp;
        float kv[4][8];
        float dot = 0.0f;
        #pragma unroll
        for (int t = 0; t < 4; t++) {
            if (t * 512 < ldp) {
                const int j8 = lane * 8 + t * 512;
                uint4 kk = {0u, 0u, 0u, 0u};
                if (j8 < ldp) kk = *reinterpret_cast<const uint4*>(Krow + j8);
                kv[t][0] = bflo(kk.x); kv[t][1] = bfhi(kk.x);
                kv[t][2] = bflo(kk.y); kv[t][3] = bfhi(kk.y);
                kv[t][4] = bflo(kk.z); kv[t][5] = bfhi(kk.z);
                kv[t][6] = bflo(kk.w); kv[t][7] = bfhi(kk.w);
                const float* wp = &w_l[j8];
                #pragma unroll
                for (int e = 0; e < 8; e++) dot += kv[t][e] * wp[e];
            } else {
                #pragma unroll
                for (int e = 0; e < 8; e++) kv[t][e] = 0.0f;
            }
        }
        for (int off = 32; off; off >>= 1) dot += __shfl_xor(dot, off);
        const float ui = ((i < nt) ? a_main : a_last) / dot;
        if (lane == 0) u[i] = ui;
        #pragma unroll
        for (int t = 0; t < 4; t++)
            #pragma unroll
            for (int e = 0; e < 8; e++) va[t][e] += kv[t][e] * ui;
    }

    // merge per-lane partials into LDS (4-way wave contention max)
    #pragma unroll
    for (int t = 0; t < 4; t++) {
        if (t * 512 < ldp) {
            const int j8 = lane * 8 + t * 512;
            #pragma unroll
            for (int e = 0; e < 8; e++) atomicAdd(&ypart[j8 + e], va[t][e]);
        }
    }
    __syncthreads();
    for (int j = tid; j <= nc; j += 256) atomicAdd(&ynxt[j], ypart[j]);
}

// ---------------------------------------------------------------------------
// 6) value: out += 2 * sum_ij u_i K_ij Mt_ij v_j  (Mt via log recovery)
__global__ __launch_bounds__(256) void value_kernel(float* __restrict__ ws, const int* __restrict__ seqlen,
                                                    float* __restrict__ out) {
    const int s = blockIdx.y, chunk = blockIdx.x;
    if (s >= *seqlen) return;
    const int nt = ((const int*)ws)[0], nc = ((const int*)ws)[1];
    const int R = nt + 1;
    const int ldp = ((nc + 1) + 7) & ~7;
    const int rpc = (R + NCHUNK - 1) / NCHUNK;
    const int r0 = chunk * rpc;
    const int rend = min(rpc, R - r0);
    if (rend <= 0) return;
    const float b_main = ws[5], b_last = ws[6];
    const float meanM = ws[OFF_SUM + s] / ((float)nt * (float)nc);   // 1/lam
    const float* y20 = ws + OFF_Y + (size_t)(20 % 3) * (S_MAX * VST) + s * VST;
    const float* u   = ws + OFF_U + s * VST;
    const int tid = threadIdx.x, lane = tid & 63, wave = tid >> 6;

    __shared__ __align__(16) float w_l[2056];
    __shared__ float wred[4];
    for (int j = tid; j < 2056; j += 256)
        w_l[j] = (j <= nc) ? (((j < nc) ? b_main : b_last) / y20[j]) : 0.0f;
    __syncthreads();

    const unsigned short* Kb = reinterpret_cast<const unsigned short*>(ws + OFF_KF) + (size_t)s * KSLOT;
    float wsum = 0.0f;
    for (int rr = wave; rr < rend; rr += 4) {
        const int i = r0 + rr;
        const unsigned short* Krow = Kb + (size_t)i * ldp;
        float acc = 0.0f;
        for (int j8 = lane * 8; j8 < ldp; j8 += 512) {   // j8+8 <= ldp always (both mult of 8)
            uint4 kk = *reinterpret_cast<const uint4*>(Krow + j8);
            float4 w0 = *reinterpret_cast<const float4*>(&w_l[j8]);
            float4 w1 = *reinterpret_cast<const float4*>(&w_l[j8 + 4]);
            float k0 = bflo(kk.x), k1 = bfhi(kk.x), k2 = bflo(kk.y), k3 = bfhi(kk.y);
            float k4 = bflo(kk.z), k5 = bfhi(kk.z), k6 = bflo(kk.w), k7 = bfhi(kk.w);
            acc += k0 * (-__logf(fmaxf(k0 - 1e-6f, 1e-30f))) * w0.x
                 + k1 * (-__logf(fmaxf(k1 - 1e-6f, 1e-30f))) * w0.y
                 + k2 * (-__logf(fmaxf(k2 - 1e-6f, 1e-30f))) * w0.z
                 + k3 * (-__logf(fmaxf(k3 - 1e-6f, 1e-30f))) * w0.w
                 + k4 * (-__logf(fmaxf(k4 - 1e-6f, 1e-30f))) * w1.x
                 + k5 * (-__logf(fmaxf(k5 - 1e-6f, 1e-30f))) * w1.y
                 + k6 * (-__logf(fmaxf(k6 - 1e-6f, 1e-30f))) * w1.z
                 + k7 * (-__logf(fmaxf(k7 - 1e-6f, 1e-30f))) * w1.w;
        }
        acc *= meanM;
        for (int off = 32; off; off >>= 1) acc += __shfl_xor(acc, off);
        wsum += u[i] * acc;
    }
    if (lane == 0) wred[wave] = wsum;
    __syncthreads();
    if (tid == 0)
        atomicAdd(out, 2.0f * (wred[0] + wred[1] + wred[2] + wred[3]));
}

// ---------------------------------------------------------------------------
extern "C" void kernel_launch(void* const* d_in, const int* in_sizes, int n_in,
                              void* d_out, int out_size, void* d_ws, size_t ws_size,
                              hipStream_t stream) {
    const float* enc  = (const float*)d_in[0];
    const int* seqlen = (const int*)d_in[1];
    const int* t      = (const int*)d_in[2];
    float* out = (float*)d_out;
    float* ws  = (float*)d_ws;

    hipMemsetAsync(d_out, 0, sizeof(float), stream);
    // zero meta/stats + y buffers 0,1 (buffer 2 zeroed inside fusedBA(0))
    hipMemsetAsync(d_ws, 0, (size_t)(OFF_Y + 2 * S_MAX * VST) * sizeof(float), stream);

    idx_kernel    <<<1, 1024, 0, stream>>>(t, ws);
    compact_kernel<<<16384, 256, 0, stream>>>(enc, ws);
    m_kernel      <<<dim3(16, 16, 32), 256, 0, stream>>>(ws);

    const dim3 pg(NCHUNK, 32);
    phaseA0_kernel<<<pg, 256, 0, stream>>>(ws);          // M->K + y0 = K^T a
    for (int k = 0; k < 20; k++)
        fusedBA_kernel<<<pg, 256, 0, stream>>>(ws, k);   // u = a/(K w); y_{k+1} = K^T u
    value_kernel  <<<pg, 256, 0, stream>>>(ws, seqlen, out);
}

// Round 6
// 770.268 us; speedup vs baseline: 8.0880x; 2.1674x over previous
//
#include <hip/hip_runtime.h>
#include <hip/hip_bf16.h>

// ---------------- workspace layout (float-element offsets) ----------------
#define S_MAX  32
#define VST    2052                   // per-s u stride
#define KSLOT  1057824                // bf16 elems per s K slot >= max (nt+1)*ldp
#define NCHUNK 16                     // row-chunks per s in Sinkhorn phases
#define YPST   2064                   // ypart row stride (floats, 16B aligned)

#define OFF_MAX  64                   // 32 uints (float bits, atomicMax of M)
#define OFF_SUM  96                   // 32 floats (atomicAdd of sum M)
#define OFF_RNK  128                  // int[2048]: pool destination row per sample
#define OFF_NORM 2176                 // float[32][2048] sq-norms -> ends 67712
#define OFF_U    67712                // float[32][VST] u vector -> ends 133376
#define OFF_POOL 133376               // bf16 pool Xall[32][2048][256] (8,388,608 floats)
#define OFF_YP   OFF_POOL             // ypart[2][32][16][YPST] aliases dead pool (8.45MB < 33.5MB)
#define OFF_KF   8521984              // bf16 K region; 32*KSLOT ushorts
// total: 8521984 + 32*KSLOT/2 = 25,447,168 floats = 101.8 MB

typedef __attribute__((ext_vector_type(8))) short bf16x8;
typedef __attribute__((ext_vector_type(4))) float f32x4;

__device__ __forceinline__ float bflo(unsigned u) { return __uint_as_float(u << 16); }
__device__ __forceinline__ float bfhi(unsigned u) { return __uint_as_float(u & 0xffff0000u); }
__device__ __forceinline__ unsigned short f2bf(float f) {
    __hip_bfloat16 h = __float2bfloat16(f);
    return *reinterpret_cast<unsigned short*>(&h);
}

// ---------------------------------------------------------------------------
// 1) index scan -> pool destination row + meta  (one block)
__global__ __launch_bounds__(1024) void idx_kernel(const int* __restrict__ t, float* __restrict__ ws) {
    __shared__ int sc[2048];
    const int tid = threadIdx.x;
    int p0 = (t[tid] > 0) ? 1 : 0;
    int p1 = (t[tid + 1024] > 0) ? 1 : 0;
    sc[tid] = p0; sc[tid + 1024] = p1;
    __syncthreads();
    for (int off = 1; off < 2048; off <<= 1) {
        int v0 = 0, v1 = 0;
        if (tid >= off)        v0 = sc[tid - off];
        if (tid + 1024 >= off) v1 = sc[tid + 1024 - off];
        __syncthreads();
        sc[tid] += v0; sc[tid + 1024] += v1;
        __syncthreads();
    }
    const int incl0 = sc[tid], incl1 = sc[tid + 1024];
    const int nt = sc[2047];
    const int nc = 2048 - nt;
    int* dst = (int*)(ws + OFF_RNK);
    dst[tid]        = p0 ? (incl0 - 1) : (2047 - (tid - incl0));
    dst[tid + 1024] = p1 ? (incl1 - 1) : (2047 - (tid + 1024 - incl1));
    if (tid == 0) {
        const float p = (float)nt / 2048.0f;
        ((int*)ws)[0] = nt;
        ((int*)ws)[1] = nc;
        ws[2] = p;
        ws[3] = p / (float)nt;            // a_main
        ws[4] = 1.0f - p;                 // a_last
        ws[5] = (1.0f - p) / (float)nc;   // b_main
        ws[6] = p;                        // b_last
    }
}

// ---------------------------------------------------------------------------
// 2) compact + cast: gather (n,s) row -> bf16 pool row dst[n]; fused sq-norm
__global__ __launch_bounds__(256) void compact_kernel(const float* __restrict__ enc, float* __restrict__ ws) {
    const int gw = blockIdx.x * 4 + (threadIdx.x >> 6);   // 0..65535
    const int lane = threadIdx.x & 63;
    const int n = gw >> 5, s = gw & 31;
    const int r = ((const int*)(ws + OFF_RNK))[n];
    const float4 v = *(const float4*)(enc + ((size_t)n * 32 + s) * 256 + lane * 4);
    float ss = v.x * v.x + v.y * v.y + v.z * v.z + v.w * v.w;
    for (int off = 32; off; off >>= 1) ss += __shfl_xor(ss, off);
    unsigned short* pool = reinterpret_cast<unsigned short*>(ws + OFF_POOL);
    ushort4 pk = { f2bf(v.x), f2bf(v.y), f2bf(v.z), f2bf(v.w) };
    *reinterpret_cast<ushort4*>(pool + ((size_t)(s * 2048 + r)) * 256 + lane * 4) = pk;
    if (lane == 0) ws[OFF_NORM + s * 2048 + r] = ss;
}

// ---------------------------------------------------------------------------
// 3) M tiles via MFMA bf16, persistent: grid (64, 32); each block loops the
//    real ceil(nt/128) x ceil(nc/128) tile list (no dead blocks).
__global__ __launch_bounds__(256) void m_kernel(float* __restrict__ ws) {
    const int s = blockIdx.y;
    const int nt = ((const int*)ws)[0], nc = ((const int*)ws)[1];
    const int ldp = ((nc + 1) + 7) & ~7;
    const int nty = (nt + 127) >> 7, ncx = (nc + 127) >> 7;
    const int ntiles = nty * ncx;

    __shared__ float nrmA[128], nrmB[128];
    __shared__ float rmax[4], rsum[4];
    const int tid = threadIdx.x;
    const int lane = tid & 63, wave = tid >> 6;
    const int wr = wave >> 1, wc = wave & 1;
    const int row16 = lane & 15, koff = (lane >> 4) * 8;
    const unsigned short* pool = reinterpret_cast<const unsigned short*>(ws + OFF_POOL);
    const size_t sbase = (size_t)s * 2048 * 256;
    unsigned short* Ks = reinterpret_cast<unsigned short*>(ws + OFF_KF) + (size_t)s * KSLOT;

    float bmax = 0.0f, bsum = 0.0f;
    for (int tp = blockIdx.x; tp < ntiles; tp += 64) {
        const int by = tp / ncx, bx = tp - by * ncx;
        const int ibase = by * 128, jbase = bx * 128;

        __syncthreads();
        if (tid < 128) {
            nrmA[tid] = ws[OFF_NORM + s * 2048 + min(ibase + tid, 2047)];
        } else {
            const int j = jbase + (tid - 128);
            nrmB[tid - 128] = ws[OFF_NORM + s * 2048 + max(2047 - j, 0)];
        }
        __syncthreads();

        f32x4 acc[4][4] = {};
        #pragma unroll
        for (int d0 = 0; d0 < 256; d0 += 32) {
            bf16x8 af[4], bg[4];
            #pragma unroll
            for (int f = 0; f < 4; f++) {
                const int ar = min(ibase + wr * 64 + f * 16 + row16, 2047);
                const int br = max(2047 - (jbase + wc * 64 + f * 16 + row16), 0);
                af[f] = *(const bf16x8*)(pool + sbase + (size_t)ar * 256 + koff + d0);
                bg[f] = *(const bf16x8*)(pool + sbase + (size_t)br * 256 + koff + d0);
            }
            #pragma unroll
            for (int fi = 0; fi < 4; fi++)
                #pragma unroll
                for (int fj = 0; fj < 4; fj++)
                    acc[fi][fj] = __builtin_amdgcn_mfma_f32_16x16x32_bf16(af[fi], bg[fj], acc[fi][fj], 0, 0, 0);
        }

        // C/D layout: col = lane&15, row = (lane>>4)*4 + e
        const int crow = (lane >> 4) * 4, ccol = lane & 15;
        #pragma unroll
        for (int fi = 0; fi < 4; fi++) {
            #pragma unroll
            for (int fj = 0; fj < 4; fj++) {
                #pragma unroll
                for (int e = 0; e < 4; e++) {
                    const int ti = wr * 64 + fi * 16 + crow + e;
                    const int tj = wc * 64 + fj * 16 + ccol;
                    const int i = ibase + ti, j = jbase + tj;
                    if (i < nt && j < nc) {
                        float m = nrmA[ti] + nrmB[tj] - 2.0f * acc[fi][fj][e];
                        Ks[(size_t)i * ldp + j] = f2bf(m);
                        bmax = fmaxf(bmax, m);
                        bsum += m;
                    }
                }
            }
        }
    }
    for (int off = 32; off; off >>= 1) {
        bmax = fmaxf(bmax, __shfl_xor(bmax, off));
        bsum += __shfl_xor(bsum, off);
    }
    if (lane == 0) { rmax[wave] = bmax; rsum[wave] = bsum; }
    __syncthreads();
    if (tid == 0) {
        float bm = fmaxf(fmaxf(rmax[0], rmax[1]), fmaxf(rmax[2], rmax[3]));
        float bs = rsum[0] + rsum[1] + rsum[2] + rsum[3];
        atomicMax(&((unsigned int*)ws)[OFF_MAX + s], __float_as_uint(bm));
        atomicAdd(&ws[OFF_SUM + s], bs);
    }
}

// ---------------------------------------------------------------------------
// 4) A0 + M->K transform: ypart[0][s][c][j] = sum_{i in chunk} K[i][j]*a_i,
//    K computed from M in place. Thread owns 8 consecutive j. No atomics.
__global__ __launch_bounds__(256) void phaseA0_kernel(float* __restrict__ ws) {
    const int s = blockIdx.y, chunk = blockIdx.x;
    const int nt = ((const int*)ws)[0], nc = ((const int*)ws)[1];
    const int R = nt + 1;
    const int ldp = ((nc + 1) + 7) & ~7;
    const int rpc = (R + NCHUNK - 1) / NCHUNK;
    const int r0 = chunk * rpc;
    const int rend = min(rpc, R - r0);
    const int j0 = threadIdx.x * 8;
    float* ypo = ws + OFF_YP + ((size_t)s * NCHUNK + chunk) * YPST;   // parity 0

    float acc[8];
    #pragma unroll
    for (int e = 0; e < 8; e++) acc[e] = 0.0f;

    if (j0 < ldp && rend > 0) {
        const float a_main = ws[3], a_last = ws[4];
        const float delta = __uint_as_float(((const unsigned int*)ws)[OFF_MAX + s]);
        const float lam = (float)nt * (float)nc / ws[OFF_SUM + s];
        const float kpad = __expf(-lam * delta) + 1e-6f;
        unsigned short* Kb = reinterpret_cast<unsigned short*>(ws + OFF_KF) + (size_t)s * KSLOT;

        #pragma unroll 2
        for (int r = 0; r < rend; r++) {
            const int i = r0 + r;
            unsigned short* Krow = Kb + (size_t)i * ldp + j0;
            uint4 kk = *reinterpret_cast<const uint4*>(Krow);
            float mv[8] = { bflo(kk.x), bfhi(kk.x), bflo(kk.y), bfhi(kk.y),
                            bflo(kk.z), bfhi(kk.z), bflo(kk.w), bfhi(kk.w) };
            const float uv = (i < nt) ? a_main : a_last;
            unsigned short pk[8];
            #pragma unroll
            for (int e = 0; e < 8; e++) {
                const int j = j0 + e;
                float kv;
                if (j > nc)       kv = 0.0f;
                else if (i == nt) kv = (j == nc) ? (1.0f + 1e-6f) : kpad;
                else if (j == nc) kv = kpad;
                else              kv = __expf(-lam * mv[e]) + 1e-6f;
                pk[e] = f2bf(kv);
                acc[e] += kv * uv;
            }
            uint4 st;
            st.x = (unsigned)pk[0] | ((unsigned)pk[1] << 16);
            st.y = (unsigned)pk[2] | ((unsigned)pk[3] << 16);
            st.z = (unsigned)pk[4] | ((unsigned)pk[5] << 16);
            st.w = (unsigned)pk[6] | ((unsigned)pk[7] << 16);
            *reinterpret_cast<uint4*>(Krow) = st;
        }
    }
    if (j0 < 2048) {
        float4 s0 = { acc[0], acc[1], acc[2], acc[3] };
        float4 s1 = { acc[4], acc[5], acc[6], acc[7] };
        *reinterpret_cast<float4*>(ypo + j0)     = s0;
        *reinterpret_cast<float4*>(ypo + j0 + 4) = s1;
    }
}

// ---------------------------------------------------------------------------
// 5) fused B(k)+A(k+1), atomic-free: w = b / (16-way sum of ypart[par]);
//    per row: dot -> u_i -> y' partial accumulation in registers; wave strips
//    merged in LDS; block writes ypart[par^1][s][chunk][*].
__global__ __launch_bounds__(256) void fusedBA_kernel(float* __restrict__ ws, int par) {
    const int s = blockIdx.y, chunk = blockIdx.x;
    const int nt = ((const int*)ws)[0], nc = ((const int*)ws)[1];
    const int R = nt + 1;
    const int ldp = ((nc + 1) + 7) & ~7;
    const int rpc = (R + NCHUNK - 1) / NCHUNK;
    const int r0 = chunk * rpc;
    const int rend = min(rpc, R - r0);
    const int tid = threadIdx.x, lane = tid & 63, wave = tid >> 6;
    const float a_main = ws[3], a_last = ws[4];
    const float b_main = ws[5], b_last = ws[6];

    __shared__ __align__(16) float w_l[2056];
    __shared__ __align__(16) float ldsm[4][2056];

    // zero merge strips
    for (int j = tid; j < 4 * 2056; j += 256) (&ldsm[0][0])[j] = 0.0f;

    // w-build: 16-way strip sum
    {
        const float* yp = ws + OFF_YP + ((size_t)par * S_MAX + s) * (NCHUNK * YPST);
        for (int j0 = tid * 4; j0 < 2056; j0 += 1024) {
            float4 wv = {0.f, 0.f, 0.f, 0.f};
            if (j0 <= nc) {
                float4 sum = {0.f, 0.f, 0.f, 0.f};
                #pragma unroll
                for (int c = 0; c < NCHUNK; c++) {
                    float4 v = *reinterpret_cast<const float4*>(yp + (size_t)c * YPST + j0);
                    sum.x += v.x; sum.y += v.y; sum.z += v.z; sum.w += v.w;
                }
                wv.x = (j0 + 0 <= nc) ? (((j0 + 0 < nc) ? b_main : b_last) / sum.x) : 0.f;
                wv.y = (j0 + 1 <= nc) ? (((j0 + 1 < nc) ? b_main : b_last) / sum.y) : 0.f;
                wv.z = (j0 + 2 <= nc) ? (((j0 + 2 < nc) ? b_main : b_last) / sum.z) : 0.f;
                wv.w = (j0 + 3 <= nc) ? (((j0 + 3 < nc) ? b_main : b_last) / sum.w) : 0.f;
            }
            *reinterpret_cast<float4*>(&w_l[j0]) = wv;
        }
    }
    __syncthreads();

    const unsigned short* Kb = reinterpret_cast<const unsigned short*>(ws + OFF_KF) + (size_t)s * KSLOT;
    float* u = ws + OFF_U + s * VST;

    float va[4][8];
    #pragma unroll
    for (int t = 0; t < 4; t++)
        #pragma unroll
        for (int e = 0; e < 8; e++) va[t][e] = 0.0f;

    for (int base = wave * 2; base < rend; base += 8) {
        const int i0 = r0 + base;
        const bool two = (base + 1 < rend);
        const int i1 = two ? (i0 + 1) : i0;
        const unsigned short* Kr0 = Kb + (size_t)i0 * ldp;
        const unsigned short* Kr1 = Kb + (size_t)i1 * ldp;

        float kf0[4][8], kf1[4][8];
        float d0 = 0.0f, d1 = 0.0f;
        #pragma unroll
        for (int t = 0; t < 4; t++) {
            const int j8 = lane * 8 + t * 512;
            if (t * 512 < ldp) {
                uint4 k0 = {0u,0u,0u,0u}, k1 = {0u,0u,0u,0u};
                if (j8 < ldp) {
                    k0 = *reinterpret_cast<const uint4*>(Kr0 + j8);
                    k1 = *reinterpret_cast<const uint4*>(Kr1 + j8);
                }
                kf0[t][0] = bflo(k0.x); kf0[t][1] = bfhi(k0.x);
                kf0[t][2] = bflo(k0.y); kf0[t][3] = bfhi(k0.y);
                kf0[t][4] = bflo(k0.z); kf0[t][5] = bfhi(k0.z);
                kf0[t][6] = bflo(k0.w); kf0[t][7] = bfhi(k0.w);
                kf1[t][0] = bflo(k1.x); kf1[t][1] = bfhi(k1.x);
                kf1[t][2] = bflo(k1.y); kf1[t][3] = bfhi(k1.y);
                kf1[t][4] = bflo(k1.z); kf1[t][5] = bfhi(k1.z);
                kf1[t][6] = bflo(k1.w); kf1[t][7] = bfhi(k1.w);
                const float* wp = &w_l[j8];
                #pragma unroll
                for (int e = 0; e < 8; e++) {
                    d0 += kf0[t][e] * wp[e];
                    d1 += kf1[t][e] * wp[e];
                }
            } else {
                #pragma unroll
                for (int e = 0; e < 8; e++) { kf0[t][e] = 0.f; kf1[t][e] = 0.f; }
            }
        }
        for (int off = 32; off; off >>= 1) {
            d0 += __shfl_xor(d0, off);
            d1 += __shfl_xor(d1, off);
        }
        const float u0 = ((i0 < nt) ? a_main : a_last) / d0;
        const float u1 = ((i1 < nt) ? a_main : a_last) / d1;
        if (lane == 0) {
            u[i0] = u0;
            if (two) u[i1] = u1;
        }
        const float u1e = two ? u1 : 0.0f;
        #pragma unroll
        for (int t = 0; t < 4; t++)
            #pragma unroll
            for (int e = 0; e < 8; e++)
                va[t][e] += kf0[t][e] * u0 + kf1[t][e] * u1e;
    }

    // merge wave strips (no atomics)
    #pragma unroll
    for (int t = 0; t < 4; t++) {
        if (t * 512 < ldp) {
            const int j8 = lane * 8 + t * 512;
            if (j8 < ldp) {
                float4 v0 = { va[t][0], va[t][1], va[t][2], va[t][3] };
                float4 v1 = { va[t][4], va[t][5], va[t][6], va[t][7] };
                *reinterpret_cast<float4*>(&ldsm[wave][j8])     = v0;
                *reinterpret_cast<float4*>(&ldsm[wave][j8 + 4]) = v1;
            }
        }
    }
    __syncthreads();

    float* ypo = ws + OFF_YP + (((size_t)(par ^ 1) * S_MAX + s) * NCHUNK + chunk) * YPST;
    for (int j0 = tid * 4; j0 < 2056; j0 += 1024) {
        float4 a0 = *reinterpret_cast<const float4*>(&ldsm[0][j0]);
        float4 a1 = *reinterpret_cast<const float4*>(&ldsm[1][j0]);
        float4 a2 = *reinterpret_cast<const float4*>(&ldsm[2][j0]);
        float4 a3 = *reinterpret_cast<const float4*>(&ldsm[3][j0]);
        float4 r;
        r.x = (a0.x + a1.x) + (a2.x + a3.x);
        r.y = (a0.y + a1.y) + (a2.y + a3.y);
        r.z = (a0.z + a1.z) + (a2.z + a3.z);
        r.w = (a0.w + a1.w) + (a2.w + a3.w);
        *reinterpret_cast<float4*>(ypo + j0) = r;
    }
}

// ---------------------------------------------------------------------------
// 6) value: out += 2 * sum_ij u_i K_ij Mt_ij v_j  (Mt via log; v from ypart[0])
__global__ __launch_bounds__(256) void value_kernel(float* __restrict__ ws, const int* __restrict__ seqlen,
                                                    float* __restrict__ out) {
    const int s = blockIdx.y, chunk = blockIdx.x;
    const int nt = ((const int*)ws)[0], nc = ((const int*)ws)[1];
    const int R = nt + 1;
    const int ldp = ((nc + 1) + 7) & ~7;
    const int rpc = (R + NCHUNK - 1) / NCHUNK;
    const int r0 = chunk * rpc;
    const int rend = min(rpc, R - r0);
    const float b_main = ws[5], b_last = ws[6];
    const float meanM = ws[OFF_SUM + s] / ((float)nt * (float)nc);   // 1/lam
    const float* u = ws + OFF_U + s * VST;
    const int tid = threadIdx.x, lane = tid & 63, wave = tid >> 6;

    __shared__ __align__(16) float w_l[2056];
    __shared__ float wred[4];
    {
        const float* yp = ws + OFF_YP + (size_t)s * (NCHUNK * YPST);   // parity 0 (y_20)
        for (int j0 = tid * 4; j0 < 2056; j0 += 1024) {
            float4 wv = {0.f, 0.f, 0.f, 0.f};
            if (j0 <= nc) {
                float4 sum = {0.f, 0.f, 0.f, 0.f};
                #pragma unroll
                for (int c = 0; c < NCHUNK; c++) {
                    float4 v = *reinterpret_cast<const float4*>(yp + (size_t)c * YPST + j0);
                    sum.x += v.x; sum.y += v.y; sum.z += v.z; sum.w += v.w;
                }
                wv.x = (j0 + 0 <= nc) ? (((j0 + 0 < nc) ? b_main : b_last) / sum.x) : 0.f;
                wv.y = (j0 + 1 <= nc) ? (((j0 + 1 < nc) ? b_main : b_last) / sum.y) : 0.f;
                wv.z = (j0 + 2 <= nc) ? (((j0 + 2 < nc) ? b_main : b_last) / sum.z) : 0.f;
                wv.w = (j0 + 3 <= nc) ? (((j0 + 3 < nc) ? b_main : b_last) / sum.w) : 0.f;
            }
            *reinterpret_cast<float4*>(&w_l[j0]) = wv;
        }
    }
    __syncthreads();

    const unsigned short* Kb = reinterpret_cast<const unsigned short*>(ws + OFF_KF) + (size_t)s * KSLOT;
    float wsum = 0.0f;
    for (int rr = wave; rr < rend; rr += 4) {
        const int i = r0 + rr;
        const unsigned short* Krow = Kb + (size_t)i * ldp;
        float acc = 0.0f;
        for (int j8 = lane * 8; j8 < ldp; j8 += 512) {
            uint4 kk = *reinterpret_cast<const uint4*>(Krow + j8);
            float4 w0 = *reinterpret_cast<const float4*>(&w_l[j8]);
            float4 w1 = *reinterpret_cast<const float4*>(&w_l[j8 + 4]);
            float k0 = bflo(kk.x), k1 = bfhi(kk.x), k2 = bflo(kk.y), k3 = bfhi(kk.y);
            float k4 = bflo(kk.z), k5 = bfhi(kk.z), k6 = bflo(kk.w), k7 = bfhi(kk.w);
            acc += k0 * (-__logf(fmaxf(k0 - 1e-6f, 1e-30f))) * w0.x
                 + k1 * (-__logf(fmaxf(k1 - 1e-6f, 1e-30f))) * w0.y
                 + k2 * (-__logf(fmaxf(k2 - 1e-6f, 1e-30f))) * w0.z
                 + k3 * (-__logf(fmaxf(k3 - 1e-6f, 1e-30f))) * w0.w
                 + k4 * (-__logf(fmaxf(k4 - 1e-6f, 1e-30f))) * w1.x
                 + k5 * (-__logf(fmaxf(k5 - 1e-6f, 1e-30f))) * w1.y
                 + k6 * (-__logf(fmaxf(k6 - 1e-6f, 1e-30f))) * w1.z
                 + k7 * (-__logf(fmaxf(k7 - 1e-6f, 1e-30f))) * w1.w;
        }
        acc *= meanM;
        for (int off = 32; off; off >>= 1) acc += __shfl_xor(acc, off);
        wsum += u[i] * acc;
    }
    if (lane == 0) wred[wave] = wsum;
    __syncthreads();
    if (tid == 0 && s < *seqlen)
        atomicAdd(out, 2.0f * (wred[0] + wred[1] + wred[2] + wred[3]));
}

// ---------------------------------------------------------------------------
extern "C" void kernel_launch(void* const* d_in, const int* in_sizes, int n_in,
                              void* d_out, int out_size, void* d_ws, size_t ws_size,
                              hipStream_t stream) {
    const float* enc  = (const float*)d_in[0];
    const int* seqlen = (const int*)d_in[1];
    const int* t      = (const int*)d_in[2];
    float* out = (float*)d_out;
    float* ws  = (float*)d_ws;

    hipMemsetAsync(d_out, 0, sizeof(float), stream);
    hipMemsetAsync(d_ws, 0, 128 * sizeof(float), stream);   // meta + max/sum stats

    idx_kernel    <<<1, 1024, 0, stream>>>(t, ws);
    compact_kernel<<<16384, 256, 0, stream>>>(enc, ws);
    m_kernel      <<<dim3(64, 32), 256, 0, stream>>>(ws);

    const dim3 pg(NCHUNK, 32);
    phaseA0_kernel<<<pg, 256, 0, stream>>>(ws);             // M->K + ypart[0] = partials of K^T a
    for (int k = 0; k < 20; k++)
        fusedBA_kernel<<<pg, 256, 0, stream>>>(ws, k & 1);  // u = a/(K w); ypart[par^1] = partials K^T u
    value_kernel  <<<pg, 256, 0, stream>>>(ws, seqlen, out);
}

// Round 7
// 747.228 us; speedup vs baseline: 8.3374x; 1.0308x over previous
//
#include <hip/hip_runtime.h>
#include <hip/hip_bf16.h>

// ---------------- workspace layout (float-element offsets) ----------------
#define S_MAX  32
#define VST    2052                   // per-s u stride
#define KSLOT  1057824                // bf16 elems per s K slot >= max (nt+1)*ldp
#define NCHUNK 16                     // row-chunks per s in Sinkhorn phases
#define YPST   2064                   // ypart row stride (floats, 16B aligned)

#define OFF_MAX  64                   // 32 uints (float bits, atomicMax of M)
#define OFF_SUM  96                   // 32 floats (atomicAdd of sum M)
#define OFF_RNK  128                  // int[2048]: pool destination row per sample
#define OFF_NORM 2176                 // float[32][2048] sq-norms -> ends 67712
#define OFF_U    67712                // float[32][VST] u vector -> ends 133376
#define OFF_POOL 133376               // bf16 pool Xall[32][2048][256] (8,388,608 floats)
#define OFF_YP   OFF_POOL             // ypart[2][32][16][YPST] aliases dead pool region
#define OFF_KF   8521984              // bf16 K region; 32*KSLOT ushorts
// total: 8521984 + 32*KSLOT/2 = 25,447,168 floats = 101.8 MB

typedef __attribute__((ext_vector_type(8))) short bf16x8;
typedef __attribute__((ext_vector_type(4))) float f32x4;

__device__ __forceinline__ float bflo(unsigned u) { return __uint_as_float(u << 16); }
__device__ __forceinline__ float bfhi(unsigned u) { return __uint_as_float(u & 0xffff0000u); }
__device__ __forceinline__ unsigned short f2bf(float f) {
    __hip_bfloat16 h = __float2bfloat16(f);
    return *reinterpret_cast<unsigned short*>(&h);
}

// ---------------------------------------------------------------------------
// 1) index scan -> pool destination row + meta  (one block)
__global__ __launch_bounds__(1024) void idx_kernel(const int* __restrict__ t, float* __restrict__ ws) {
    __shared__ int sc[2048];
    const int tid = threadIdx.x;
    int p0 = (t[tid] > 0) ? 1 : 0;
    int p1 = (t[tid + 1024] > 0) ? 1 : 0;
    sc[tid] = p0; sc[tid + 1024] = p1;
    __syncthreads();
    for (int off = 1; off < 2048; off <<= 1) {
        int v0 = 0, v1 = 0;
        if (tid >= off)        v0 = sc[tid - off];
        if (tid + 1024 >= off) v1 = sc[tid + 1024 - off];
        __syncthreads();
        sc[tid] += v0; sc[tid + 1024] += v1;
        __syncthreads();
    }
    const int incl0 = sc[tid], incl1 = sc[tid + 1024];
    const int nt = sc[2047];
    const int nc = 2048 - nt;
    int* dst = (int*)(ws + OFF_RNK);
    dst[tid]        = p0 ? (incl0 - 1) : (2047 - (tid - incl0));
    dst[tid + 1024] = p1 ? (incl1 - 1) : (2047 - (tid + 1024 - incl1));
    if (tid == 0) {
        const float p = (float)nt / 2048.0f;
        ((int*)ws)[0] = nt;
        ((int*)ws)[1] = nc;
        ws[2] = p;
        ws[3] = p / (float)nt;            // a_main
        ws[4] = 1.0f - p;                 // a_last
        ws[5] = (1.0f - p) / (float)nc;   // b_main
        ws[6] = p;                        // b_last
    }
}

// ---------------------------------------------------------------------------
// 2) compact + cast: gather (n,s) row -> bf16 pool row dst[n]; fused sq-norm
__global__ __launch_bounds__(256) void compact_kernel(const float* __restrict__ enc, float* __restrict__ ws) {
    const int gw = blockIdx.x * 4 + (threadIdx.x >> 6);   // 0..65535
    const int lane = threadIdx.x & 63;
    const int n = gw >> 5, s = gw & 31;
    const int r = ((const int*)(ws + OFF_RNK))[n];
    const float4 v = *(const float4*)(enc + ((size_t)n * 32 + s) * 256 + lane * 4);
    float ss = v.x * v.x + v.y * v.y + v.z * v.z + v.w * v.w;
    for (int off = 32; off; off >>= 1) ss += __shfl_xor(ss, off);
    unsigned short* pool = reinterpret_cast<unsigned short*>(ws + OFF_POOL);
    ushort4 pk = { f2bf(v.x), f2bf(v.y), f2bf(v.z), f2bf(v.w) };
    *reinterpret_cast<ushort4*>(pool + ((size_t)(s * 2048 + r)) * 256 + lane * 4) = pk;
    if (lane == 0) ws[OFF_NORM + s * 2048 + r] = ss;
}

// ---------------------------------------------------------------------------
// 3) M tiles via MFMA bf16, LDS-staged 128x128 tile, BK=64, pad 64->72 shorts
//    (row stride 144B: ds_read_b128 banks 4r%32 conflict-free per 8-lane group).
__global__ __launch_bounds__(256) void m_kernel(float* __restrict__ ws) {
    const int s = blockIdx.y;
    const int nt = ((const int*)ws)[0], nc = ((const int*)ws)[1];
    const int ldp = ((nc + 1) + 7) & ~7;
    const int nty = (nt + 127) >> 7, ncx = (nc + 127) >> 7;
    const int ntiles = nty * ncx;

    __shared__ unsigned short As[128][72];
    __shared__ unsigned short Bs[128][72];
    __shared__ float nrmA[128], nrmB[128];
    __shared__ float rmax[4], rsum[4];
    const int tid = threadIdx.x;
    const int lane = tid & 63, wave = tid >> 6;
    const int wr = wave >> 1, wc = wave & 1;
    const int row16 = lane & 15, koff = (lane >> 4) * 8;
    const unsigned short* pool = reinterpret_cast<const unsigned short*>(ws + OFF_POOL);
    const size_t sbase = (size_t)s * 2048 * 256;
    unsigned short* Ks = reinterpret_cast<unsigned short*>(ws + OFF_KF) + (size_t)s * KSLOT;

    const int srow = tid >> 3, scg = (tid & 7) * 8;   // stager: 32 rows per 256-thr pass

    float bmax = 0.0f, bsum = 0.0f;
    for (int tp = blockIdx.x; tp < ntiles; tp += 64) {
        const int by = tp / ncx, bx = tp - by * ncx;
        const int ibase = by * 128, jbase = bx * 128;

        __syncthreads();   // previous tile fully done (incl. epilogue nrm reads)
        if (tid < 128) {
            nrmA[tid] = ws[OFF_NORM + s * 2048 + min(ibase + tid, 2047)];
        } else {
            const int j = jbase + (tid - 128);
            nrmB[tid - 128] = ws[OFF_NORM + s * 2048 + max(2047 - j, 0)];
        }

        f32x4 acc[4][4] = {};
        #pragma unroll
        for (int d0 = 0; d0 < 256; d0 += 64) {
            __syncthreads();   // frag reads of previous k-step done
            #pragma unroll
            for (int it = 0; it < 4; it++) {
                const int row = it * 32 + srow;
                const int ar = min(ibase + row, 2047);
                const int br = max(2047 - (jbase + row), 0);
                *reinterpret_cast<uint4*>(&As[row][scg]) =
                    *reinterpret_cast<const uint4*>(pool + sbase + (size_t)ar * 256 + d0 + scg);
                *reinterpret_cast<uint4*>(&Bs[row][scg]) =
                    *reinterpret_cast<const uint4*>(pool + sbase + (size_t)br * 256 + d0 + scg);
            }
            __syncthreads();
            #pragma unroll
            for (int ks = 0; ks < 2; ks++) {
                bf16x8 af[4], bg[4];
                #pragma unroll
                for (int f = 0; f < 4; f++) {
                    af[f] = *reinterpret_cast<const bf16x8*>(&As[wr * 64 + f * 16 + row16][ks * 32 + koff]);
                    bg[f] = *reinterpret_cast<const bf16x8*>(&Bs[wc * 64 + f * 16 + row16][ks * 32 + koff]);
                }
                #pragma unroll
                for (int fi = 0; fi < 4; fi++)
                    #pragma unroll
                    for (int fj = 0; fj < 4; fj++)
                        acc[fi][fj] = __builtin_amdgcn_mfma_f32_16x16x32_bf16(af[fi], bg[fj], acc[fi][fj], 0, 0, 0);
            }
        }

        // C/D layout: col = lane&15, row = (lane>>4)*4 + e
        const int crow = (lane >> 4) * 4, ccol = lane & 15;
        #pragma unroll
        for (int fi = 0; fi < 4; fi++) {
            #pragma unroll
            for (int fj = 0; fj < 4; fj++) {
                #pragma unroll
                for (int e = 0; e < 4; e++) {
                    const int ti = wr * 64 + fi * 16 + crow + e;
                    const int tj = wc * 64 + fj * 16 + ccol;
                    const int i = ibase + ti, j = jbase + tj;
                    if (i < nt && j < nc) {
                        float m = nrmA[ti] + nrmB[tj] - 2.0f * acc[fi][fj][e];
                        Ks[(size_t)i * ldp + j] = f2bf(m);
                        bmax = fmaxf(bmax, m);
                        bsum += m;
                    }
                }
            }
        }
    }
    for (int off = 32; off; off >>= 1) {
        bmax = fmaxf(bmax, __shfl_xor(bmax, off));
        bsum += __shfl_xor(bsum, off);
    }
    if (lane == 0) { rmax[wave] = bmax; rsum[wave] = bsum; }
    __syncthreads();
    if (tid == 0) {
        float bm = fmaxf(fmaxf(rmax[0], rmax[1]), fmaxf(rmax[2], rmax[3]));
        float bs = rsum[0] + rsum[1] + rsum[2] + rsum[3];
        atomicMax(&((unsigned int*)ws)[OFF_MAX + s], __float_as_uint(bm));
        atomicAdd(&ws[OFF_SUM + s], bs);
    }
}

// ---------------------------------------------------------------------------
// 4) A0 + M->K transform: ypart[0][s][c][j] = sum_{i in chunk} K[i][j]*a_i
__global__ __launch_bounds__(256) void phaseA0_kernel(float* __restrict__ ws) {
    const int s = blockIdx.y, chunk = blockIdx.x;
    const int nt = ((const int*)ws)[0], nc = ((const int*)ws)[1];
    const int R = nt + 1;
    const int ldp = ((nc + 1) + 7) & ~7;
    const int rpc = (R + NCHUNK - 1) / NCHUNK;
    const int r0 = chunk * rpc;
    const int rend = min(rpc, R - r0);
    const int j0 = threadIdx.x * 8;
    float* ypo = ws + OFF_YP + ((size_t)s * NCHUNK + chunk) * YPST;   // parity 0

    float acc[8];
    #pragma unroll
    for (int e = 0; e < 8; e++) acc[e] = 0.0f;

    if (j0 < ldp && rend > 0) {
        const float a_main = ws[3], a_last = ws[4];
        const float delta = __uint_as_float(((const unsigned int*)ws)[OFF_MAX + s]);
        const float lam = (float)nt * (float)nc / ws[OFF_SUM + s];
        const float kpad = __expf(-lam * delta) + 1e-6f;
        unsigned short* Kb = reinterpret_cast<unsigned short*>(ws + OFF_KF) + (size_t)s * KSLOT;

        #pragma unroll 2
        for (int r = 0; r < rend; r++) {
            const int i = r0 + r;
            unsigned short* Krow = Kb + (size_t)i * ldp + j0;
            uint4 kk = *reinterpret_cast<const uint4*>(Krow);
            float mv[8] = { bflo(kk.x), bfhi(kk.x), bflo(kk.y), bfhi(kk.y),
                            bflo(kk.z), bfhi(kk.z), bflo(kk.w), bfhi(kk.w) };
            const float uv = (i < nt) ? a_main : a_last;
            unsigned short pk[8];
            #pragma unroll
            for (int e = 0; e < 8; e++) {
                const int j = j0 + e;
                float kv;
                if (j > nc)       kv = 0.0f;
                else if (i == nt) kv = (j == nc) ? (1.0f + 1e-6f) : kpad;
                else if (j == nc) kv = kpad;
                else              kv = __expf(-lam * mv[e]) + 1e-6f;
                pk[e] = f2bf(kv);
                acc[e] += kv * uv;
            }
            uint4 st;
            st.x = (unsigned)pk[0] | ((unsigned)pk[1] << 16);
            st.y = (unsigned)pk[2] | ((unsigned)pk[3] << 16);
            st.z = (unsigned)pk[4] | ((unsigned)pk[5] << 16);
            st.w = (unsigned)pk[6] | ((unsigned)pk[7] << 16);
            *reinterpret_cast<uint4*>(Krow) = st;
        }
    }
    if (j0 < 2048) {
        float4 s0 = { acc[0], acc[1], acc[2], acc[3] };
        float4 s1 = { acc[4], acc[5], acc[6], acc[7] };
        *reinterpret_cast<float4*>(ypo + j0)     = s0;
        *reinterpret_cast<float4*>(ypo + j0 + 4) = s1;
    }
}

// ---------------------------------------------------------------------------
// 5) fused B(k)+A(k+1), atomic-free, 4-row/wave unroll for ILP.
__global__ __launch_bounds__(256) void fusedBA_kernel(float* __restrict__ ws, int par) {
    const int s = blockIdx.y, chunk = blockIdx.x;
    const int nt = ((const int*)ws)[0], nc = ((const int*)ws)[1];
    const int R = nt + 1;
    const int ldp = ((nc + 1) + 7) & ~7;
    const int rpc = (R + NCHUNK - 1) / NCHUNK;
    const int r0 = chunk * rpc;
    const int rend = min(rpc, R - r0);
    const int tid = threadIdx.x, lane = tid & 63, wave = tid >> 6;
    const float a_main = ws[3], a_last = ws[4];
    const float b_main = ws[5], b_last = ws[6];

    __shared__ __align__(16) float w_l[2056];
    __shared__ __align__(16) float ldsm[4][2056];

    for (int j = tid; j < 4 * 2056; j += 256) (&ldsm[0][0])[j] = 0.0f;

    // w-build: 16-way strip sum
    {
        const float* yp = ws + OFF_YP + ((size_t)par * S_MAX + s) * (NCHUNK * YPST);
        for (int j0 = tid * 4; j0 < 2056; j0 += 1024) {
            float4 wv = {0.f, 0.f, 0.f, 0.f};
            if (j0 <= nc) {
                float4 sum = {0.f, 0.f, 0.f, 0.f};
                #pragma unroll
                for (int c = 0; c < NCHUNK; c++) {
                    float4 v = *reinterpret_cast<const float4*>(yp + (size_t)c * YPST + j0);
                    sum.x += v.x; sum.y += v.y; sum.z += v.z; sum.w += v.w;
                }
                wv.x = (j0 + 0 <= nc) ? (((j0 + 0 < nc) ? b_main : b_last) / sum.x) : 0.f;
                wv.y = (j0 + 1 <= nc) ? (((j0 + 1 < nc) ? b_main : b_last) / sum.y) : 0.f;
                wv.z = (j0 + 2 <= nc) ? (((j0 + 2 < nc) ? b_main : b_last) / sum.z) : 0.f;
                wv.w = (j0 + 3 <= nc) ? (((j0 + 3 < nc) ? b_main : b_last) / sum.w) : 0.f;
            }
            *reinterpret_cast<float4*>(&w_l[j0]) = wv;
        }
    }
    __syncthreads();

    const unsigned short* Kb = reinterpret_cast<const unsigned short*>(ws + OFF_KF) + (size_t)s * KSLOT;
    float* u = ws + OFF_U + s * VST;

    float va[4][8];
    #pragma unroll
    for (int t = 0; t < 4; t++)
        #pragma unroll
        for (int e = 0; e < 8; e++) va[t][e] = 0.0f;

    for (int base = wave * 4; base < rend; base += 16) {
        int ii[4]; bool act[4];
        const unsigned short* Kr[4];
        #pragma unroll
        for (int r = 0; r < 4; r++) {
            act[r] = (base + r) < rend;
            ii[r] = r0 + (act[r] ? (base + r) : base);
            Kr[r] = Kb + (size_t)ii[r] * ldp;
        }
        float kf[4][4][8];
        float d[4] = {0.f, 0.f, 0.f, 0.f};
        #pragma unroll
        for (int t = 0; t < 4; t++) {
            const int j8 = lane * 8 + t * 512;
            if (t * 512 < ldp) {
                const bool in = (j8 < ldp);
                float wreg[8];
                #pragma unroll
                for (int e = 0; e < 8; e++) wreg[e] = in ? w_l[j8 + e] : 0.0f;
                #pragma unroll
                for (int r = 0; r < 4; r++) {
                    uint4 kk = {0u, 0u, 0u, 0u};
                    if (in) kk = *reinterpret_cast<const uint4*>(Kr[r] + j8);
                    kf[r][t][0] = bflo(kk.x); kf[r][t][1] = bfhi(kk.x);
                    kf[r][t][2] = bflo(kk.y); kf[r][t][3] = bfhi(kk.y);
                    kf[r][t][4] = bflo(kk.z); kf[r][t][5] = bfhi(kk.z);
                    kf[r][t][6] = bflo(kk.w); kf[r][t][7] = bfhi(kk.w);
                    #pragma unroll
                    for (int e = 0; e < 8; e++) d[r] += kf[r][t][e] * wreg[e];
                }
            } else {
                #pragma unroll
                for (int r = 0; r < 4; r++)
                    #pragma unroll
                    for (int e = 0; e < 8; e++) kf[r][t][e] = 0.0f;
            }
        }
        for (int off = 32; off; off >>= 1) {
            d[0] += __shfl_xor(d[0], off);
            d[1] += __shfl_xor(d[1], off);
            d[2] += __shfl_xor(d[2], off);
            d[3] += __shfl_xor(d[3], off);
        }
        float uu[4];
        #pragma unroll
        for (int r = 0; r < 4; r++)
            uu[r] = act[r] ? (((ii[r] < nt) ? a_main : a_last) / d[r]) : 0.0f;
        if (lane == 0) {
            #pragma unroll
            for (int r = 0; r < 4; r++) if (act[r]) u[ii[r]] = uu[r];
        }
        #pragma unroll
        for (int t = 0; t < 4; t++)
            #pragma unroll
            for (int e = 0; e < 8; e++)
                va[t][e] += kf[0][t][e] * uu[0] + kf[1][t][e] * uu[1]
                          + kf[2][t][e] * uu[2] + kf[3][t][e] * uu[3];
    }

    // merge wave strips (no atomics)
    #pragma unroll
    for (int t = 0; t < 4; t++) {
        const int j8 = lane * 8 + t * 512;
        if (t * 512 < ldp && j8 < ldp) {
            float4 v0 = { va[t][0], va[t][1], va[t][2], va[t][3] };
            float4 v1 = { va[t][4], va[t][5], va[t][6], va[t][7] };
            *reinterpret_cast<float4*>(&ldsm[wave][j8])     = v0;
            *reinterpret_cast<float4*>(&ldsm[wave][j8 + 4]) = v1;
        }
    }
    __syncthreads();

    float* ypo = ws + OFF_YP + (((size_t)(par ^ 1) * S_MAX + s) * NCHUNK + chunk) * YPST;
    for (int j0 = tid * 4; j0 < 2056; j0 += 1024) {
        float4 a0 = *reinterpret_cast<const float4*>(&ldsm[0][j0]);
        float4 a1 = *reinterpret_cast<const float4*>(&ldsm[1][j0]);
        float4 a2 = *reinterpret_cast<const float4*>(&ldsm[2][j0]);
        float4 a3 = *reinterpret_cast<const float4*>(&ldsm[3][j0]);
        float4 r;
        r.x = (a0.x + a1.x) + (a2.x + a3.x);
        r.y = (a0.y + a1.y) + (a2.y + a3.y);
        r.z = (a0.z + a1.z) + (a2.z + a3.z);
        r.w = (a0.w + a1.w) + (a2.w + a3.w);
        *reinterpret_cast<float4*>(ypo + j0) = r;
    }
}

// ---------------------------------------------------------------------------
// 6) value: out += 2 * sum_ij u_i K_ij Mt_ij v_j  (Mt via log; v from ypart[0])
__global__ __launch_bounds__(256) void value_kernel(float* __restrict__ ws, const int* __restrict__ seqlen,
                                                    float* __restrict__ out) {
    const int s = blockIdx.y, chunk = blockIdx.x;
    const int nt = ((const int*)ws)[0], nc = ((const int*)ws)[1];
    const int R = nt + 1;
    const int ldp = ((nc + 1) + 7) & ~7;
    const int rpc = (R + NCHUNK - 1) / NCHUNK;
    const int r0 = chunk * rpc;
    const int rend = min(rpc, R - r0);
    const float b_main = ws[5], b_last = ws[6];
    const float meanM = ws[OFF_SUM + s] / ((float)nt * (float)nc);   // 1/lam
    const float* u = ws + OFF_U + s * VST;
    const int tid = threadIdx.x, lane = tid & 63, wave = tid >> 6;

    __shared__ __align__(16) float w_l[2056];
    __shared__ float wred[4];
    {
        const float* yp = ws + OFF_YP + (size_t)s * (NCHUNK * YPST);   // parity 0 (y_20)
        for (int j0 = tid * 4; j0 < 2056; j0 += 1024) {
            float4 wv = {0.f, 0.f, 0.f, 0.f};
            if (j0 <= nc) {
                float4 sum = {0.f, 0.f, 0.f, 0.f};
                #pragma unroll
                for (int c = 0; c < NCHUNK; c++) {
                    float4 v = *reinterpret_cast<const float4*>(yp + (size_t)c * YPST + j0);
                    sum.x += v.x; sum.y += v.y; sum.z += v.z; sum.w += v.w;
                }
                wv.x = (j0 + 0 <= nc) ? (((j0 + 0 < nc) ? b_main : b_last) / sum.x) : 0.f;
                wv.y = (j0 + 1 <= nc) ? (((j0 + 1 < nc) ? b_main : b_last) / sum.y) : 0.f;
                wv.z = (j0 + 2 <= nc) ? (((j0 + 2 < nc) ? b_main : b_last) / sum.z) : 0.f;
                wv.w = (j0 + 3 <= nc) ? (((j0 + 3 < nc) ? b_main : b_last) / sum.w) : 0.f;
            }
            *reinterpret_cast<float4*>(&w_l[j0]) = wv;
        }
    }
    __syncthreads();

    const unsigned short* Kb = reinterpret_cast<const unsigned short*>(ws + OFF_KF) + (size_t)s * KSLOT;
    float wsum = 0.0f;
    for (int rr = wave; rr < rend; rr += 4) {
        const int i = r0 + rr;
        const unsigned short* Krow = Kb + (size_t)i * ldp;
        float acc = 0.0f;
        for (int j8 = lane * 8; j8 < ldp; j8 += 512) {
            uint4 kk = *reinterpret_cast<const uint4*>(Krow + j8);
            float4 w0 = *reinterpret_cast<const float4*>(&w_l[j8]);
            float4 w1 = *reinterpret_cast<const float4*>(&w_l[j8 + 4]);
            float k0 = bflo(kk.x), k1 = bfhi(kk.x), k2 = bflo(kk.y), k3 = bfhi(kk.y);
            float k4 = bflo(kk.z), k5 = bfhi(kk.z), k6 = bflo(kk.w), k7 = bfhi(kk.w);
            acc += k0 * (-__logf(fmaxf(k0 - 1e-6f, 1e-30f))) * w0.x
                 + k1 * (-__logf(fmaxf(k1 - 1e-6f, 1e-30f))) * w0.y
                 + k2 * (-__logf(fmaxf(k2 - 1e-6f, 1e-30f))) * w0.z
                 + k3 * (-__logf(fmaxf(k3 - 1e-6f, 1e-30f))) * w0.w
                 + k4 * (-__logf(fmaxf(k4 - 1e-6f, 1e-30f))) * w1.x
                 + k5 * (-__logf(fmaxf(k5 - 1e-6f, 1e-30f))) * w1.y
                 + k6 * (-__logf(fmaxf(k6 - 1e-6f, 1e-30f))) * w1.z
                 + k7 * (-__logf(fmaxf(k7 - 1e-6f, 1e-30f))) * w1.w;
        }
        acc *= meanM;
        for (int off = 32; off; off >>= 1) acc += __shfl_xor(acc, off);
        wsum += u[i] * acc;
    }
    if (lane == 0) wred[wave] = wsum;
    __syncthreads();
    if (tid == 0 && s < *seqlen)
        atomicAdd(out, 2.0f * (wred[0] + wred[1] + wred[2] + wred[3]));
}

// ---------------------------------------------------------------------------
extern "C" void kernel_launch(void* const* d_in, const int* in_sizes, int n_in,
                              void* d_out, int out_size, void* d_ws, size_t ws_size,
                              hipStream_t stream) {
    const float* enc  = (const float*)d_in[0];
    const int* seqlen = (const int*)d_in[1];
    const int* t      = (const int*)d_in[2];
    float* out = (float*)d_out;
    float* ws  = (float*)d_ws;

    hipMemsetAsync(d_out, 0, sizeof(float), stream);
    hipMemsetAsync(d_ws, 0, 128 * sizeof(float), stream);   // meta + max/sum stats

    idx_kernel    <<<1, 1024, 0, stream>>>(t, ws);
    compact_kernel<<<16384, 256, 0, stream>>>(enc, ws);
    m_kernel      <<<dim3(64, 32), 256, 0, stream>>>(ws);

    const dim3 pg(NCHUNK, 32);
    phaseA0_kernel<<<pg, 256, 0, stream>>>(ws);             // M->K + ypart[0] = partials of K^T a
    for (int k = 0; k < 20; k++)
        fusedBA_kernel<<<pg, 256, 0, stream>>>(ws, k & 1);  // u = a/(K w); ypart[par^1] = partials K^T u
    value_kernel  <<<pg, 256, 0, stream>>>(ws, seqlen, out);
}